// Round 1
// baseline (2686.802 us; speedup 1.0000x reference)
//
#include <hip/hip_runtime.h>
#include <stdint.h>

#define TC 8
#define WS_OFF_F    67108864ull   // PT region: 64MB max (256 chains * 128 slices * 2KB)
#define WS_OFF_MARG 71303168ull   // F region: 4MB max; marg region: 16MB

// ---------- helpers ----------
static __device__ __forceinline__ float lse32(const float* sh_prev, int h, const float* x,
                                              float igl2, float gln2, float uval)
{
  // u + gamma*ln( sum over 32 states of exp((prev_i + x_i)/gamma) ), this lane holds 16, other half via shfl
  const float4* fp = (const float4*)(sh_prev + h * 16);
  float4 A = fp[0], B = fp[1], C = fp[2], D = fp[3];
  float v[16];
  v[0]=A.x+x[0];  v[1]=A.y+x[1];  v[2]=A.z+x[2];  v[3]=A.w+x[3];
  v[4]=B.x+x[4];  v[5]=B.y+x[5];  v[6]=B.z+x[6];  v[7]=B.w+x[7];
  v[8]=C.x+x[8];  v[9]=C.y+x[9];  v[10]=C.z+x[10];v[11]=C.w+x[11];
  v[12]=D.x+x[12];v[13]=D.y+x[13];v[14]=D.z+x[14];v[15]=D.w+x[15];
  float a0=fmaxf(v[0],v[8]), a1=fmaxf(v[1],v[9]), a2=fmaxf(v[2],v[10]), a3=fmaxf(v[3],v[11]);
  float a4=fmaxf(v[4],v[12]),a5=fmaxf(v[5],v[13]),a6=fmaxf(v[6],v[14]),a7=fmaxf(v[7],v[15]);
  float b0=fmaxf(a0,a4), b1=fmaxf(a1,a5), b2=fmaxf(a2,a6), b3=fmaxf(a3,a7);
  float m = fmaxf(fmaxf(b0,b1), fmaxf(b2,b3));
  float e0 = exp2f((v[0]-m)*igl2) + exp2f((v[1]-m)*igl2);
  float e1 = exp2f((v[2]-m)*igl2) + exp2f((v[3]-m)*igl2);
  float e2 = exp2f((v[4]-m)*igl2) + exp2f((v[5]-m)*igl2);
  float e3 = exp2f((v[6]-m)*igl2) + exp2f((v[7]-m)*igl2);
  float e4 = exp2f((v[8]-m)*igl2) + exp2f((v[9]-m)*igl2);
  float e5 = exp2f((v[10]-m)*igl2) + exp2f((v[11]-m)*igl2);
  float e6 = exp2f((v[12]-m)*igl2) + exp2f((v[13]-m)*igl2);
  float e7 = exp2f((v[14]-m)*igl2) + exp2f((v[15]-m)*igl2);
  float s = ((e0+e1)+(e2+e3)) + ((e4+e5)+(e6+e7));
  float mo = __shfl_xor(m, 32);
  float m2 = fmaxf(m, mo);
  float sadj = s * exp2f((m - m2) * igl2);
  float stot = sadj + __shfl_xor(sadj, 32);
  return uval + m2 + gln2 * __log2f(stot);
}

static __device__ __forceinline__ float softmax32(float z)
{
  float zm = z;
  zm = fmaxf(zm, __shfl_xor(zm, 16));
  zm = fmaxf(zm, __shfl_xor(zm, 8));
  zm = fmaxf(zm, __shfl_xor(zm, 4));
  zm = fmaxf(zm, __shfl_xor(zm, 2));
  zm = fmaxf(zm, __shfl_xor(zm, 1));
  float p = exp2f((z - zm) * 1.4426950408889634f);
  float ps = p;
  ps += __shfl_xor(ps, 16);
  ps += __shfl_xor(ps, 8);
  ps += __shfl_xor(ps, 4);
  ps += __shfl_xor(ps, 2);
  ps += __shfl_xor(ps, 1);
  return p / ps;
}

// ---------- transpose: pw(f32, [B,32i,32j,...]) -> PT(bf16, [chain][t][j][i-xor-swizzled]) ----------
// horizontal: element (b,i,j,l,t) at p*(L*Tt) + l*Tt + t  (fixed=l, fStride=Tt, x=t, Xtot=Tt)
// vertical:   element (b,i,j,t,l) at p*(L*Tt) + t*L  + l  (fixed=t, fStride=L,  x=l, Xtot=L)
__global__ __launch_bounds__(256) void k_transpose(
    const float* __restrict__ pw, uint16_t* __restrict__ PT,
    int L, int Tt, int Tpad, int fStride, int Xtot, int dirV)
{
  __shared__ uint16_t tile[1024][33];
  int tid = threadIdx.x;
  int x0 = blockIdx.x * 32;
  int fixed = blockIdx.y;
  int b = blockIdx.z;
  size_t bbase = (size_t)b * 1024 * L * Tt;
  int xx = tid & 31, ps = tid >> 5;
  int x = x0 + xx;
  bool xok = x < Xtot;
  size_t rowoff = bbase + (size_t)fixed * fStride + x;
  size_t pstride = (size_t)L * Tt;
  #pragma unroll 4
  for (int pg = 0; pg < 1024; pg += 8) {
    int p = pg + ps;
    float v = xok ? pw[rowoff + (size_t)p * pstride] : 0.0f;
    uint32_t u = __float_as_uint(v);
    tile[p][xx] = (uint16_t)((u + 0x7FFFu + ((u >> 16) & 1u)) >> 16);  // RNE to bf16
  }
  __syncthreads();
  for (int w = 0; w < 64; w++) {
    int gidx = w * 256 + tid;       // 0..16383 : 32 slices * 512 dwords
    int xs = gidx >> 9;
    int d  = gidx & 511;
    int j   = d >> 4;
    int pos = (d >> 2) & 3;
    int dw  = d & 3;
    int c = pos ^ (j & 3);
    int i = c * 8 + dw * 2;
    uint32_t v0 = tile[i * 32 + j][xs];
    uint32_t v1 = tile[(i + 1) * 32 + j][xs];
    uint32_t pk = v0 | (v1 << 16);
    int xv = x0 + xs;
    if (xv >= Xtot) continue;
    int chain, tsl;
    if (dirV) { chain = b * L + xv;    tsl = fixed; }
    else      { chain = b * L + fixed; tsl = xv;    }
    ((uint32_t*)PT)[((size_t)chain * Tpad + tsl) * 512 + d] = pk;
  }
}

// ---------- forward DP: one wave per chain ----------
__global__ __launch_bounds__(64) void k_fwd(
    const uint16_t* __restrict__ PT, const float* __restrict__ U,
    float* __restrict__ F, const float* __restrict__ gamma,
    int L, int T, int Tt, int Tpad, int dirV)
{
  __shared__ __align__(16) unsigned char lds[2 * 16384 + 256];
  float* f_sh = (float*)(lds + 2 * 16384);
  int chain = blockIdx.x;
  int b = chain / L, l = chain - b * L;
  int tid = threadIdx.x, j = tid & 31, h = tid >> 5;
  float g = fmaxf(gamma[0], 0.01f);
  float ig = 1.0f / g;
  float igl2 = ig * 1.4426950408889634f;
  float gln2 = g * 0.6931471805599453f;
  size_t LT = (size_t)L * T;
  size_t ubase = (size_t)b * 32 * LT + (size_t)l * (dirV ? 1 : T) + (size_t)j * LT;
  int ust = dirV ? L : 1;
  float* Fc = F + (size_t)chain * T * 32;
  float f0 = U[ubase];
  if (h == 0) { f_sh[j] = f0; Fc[j] = f0; }
  const float4* src = (const float4*)(PT + (size_t)chain * Tpad * 1024);
  int nch = Tpad / TC;
  float4 stg[16];
  #pragma unroll
  for (int q = 0; q < 16; q++) stg[q] = src[q * 64 + tid];
  int cur = 0;
  for (int ch = 0; ch < nch; ch++) {
    float4* dst = (float4*)(lds + (ch & 1) * 16384);
    #pragma unroll
    for (int q = 0; q < 16; q++) dst[q * 64 + tid] = stg[q];
    if (ch + 1 < nch) {
      const float4* s2 = src + (size_t)(ch + 1) * 1024;
      #pragma unroll
      for (int q = 0; q < 16; q++) stg[q] = s2[q * 64 + tid];
    }
    int s0 = ch * TC;
    for (int ss = 0; ss < TC; ss++) {
      int s = s0 + ss;
      if (s >= Tt) break;
      const uint4* rowp = (const uint4*)(lds + (ch & 1) * 16384 + ss * 2048 + j * 64);
      uint4 r0 = rowp[(2 * h) ^ (j & 3)];
      uint4 r1 = rowp[(2 * h + 1) ^ (j & 3)];
      float x[16];
      x[0]=__uint_as_float(r0.x<<16); x[1]=__uint_as_float(r0.x&0xFFFF0000u);
      x[2]=__uint_as_float(r0.y<<16); x[3]=__uint_as_float(r0.y&0xFFFF0000u);
      x[4]=__uint_as_float(r0.z<<16); x[5]=__uint_as_float(r0.z&0xFFFF0000u);
      x[6]=__uint_as_float(r0.w<<16); x[7]=__uint_as_float(r0.w&0xFFFF0000u);
      x[8]=__uint_as_float(r1.x<<16); x[9]=__uint_as_float(r1.x&0xFFFF0000u);
      x[10]=__uint_as_float(r1.y<<16);x[11]=__uint_as_float(r1.y&0xFFFF0000u);
      x[12]=__uint_as_float(r1.z<<16);x[13]=__uint_as_float(r1.z&0xFFFF0000u);
      x[14]=__uint_as_float(r1.w<<16);x[15]=__uint_as_float(r1.w&0xFFFF0000u);
      int t = s + 1;
      float uval = U[ubase + (size_t)t * ust];
      float fnew = lse32(f_sh + cur * 32, h, x, igl2, gln2, uval);
      if (h == 0) { f_sh[(cur ^ 1) * 32 + j] = fnew; Fc[(size_t)t * 32 + j] = fnew; }
      cur ^= 1;
    }
  }
}

// ---------- backward DP + fused marginals ----------
__global__ __launch_bounds__(64) void k_bwd(
    const uint16_t* __restrict__ PT, const float* __restrict__ U,
    const float* __restrict__ F, float* __restrict__ MG,
    const float* __restrict__ gamma,
    int L, int T, int Tt, int Tpad, int dirV)
{
  __shared__ __align__(16) unsigned char lds[2 * 16384 + 256];
  float* b_sh = (float*)(lds + 2 * 16384);
  int chain = blockIdx.x;
  int b = chain / L, l = chain - b * L;
  int tid = threadIdx.x, i = tid & 31, h = tid >> 5;
  float g = fmaxf(gamma[0], 0.01f);
  float ig = 1.0f / g;
  float igl2 = ig * 1.4426950408889634f;
  float gln2 = g * 0.6931471805599453f;
  size_t LT = (size_t)L * T;
  size_t ubase = (size_t)b * 32 * LT + (size_t)l * (dirV ? 1 : T) + (size_t)i * LT;
  int ust = dirV ? L : 1;
  const float* Fc = F + (size_t)chain * T * 32;
  const float4* src = (const float4*)(PT + (size_t)chain * Tpad * 1024);
  int nch = Tpad / TC;
  float4 stg[16];
  {
    const float4* s2 = src + (size_t)(nch - 1) * 1024;
    #pragma unroll
    for (int q = 0; q < 16; q++) stg[q] = s2[q * 64 + tid];
  }
  // prologue t = T-1 : b = u, marg = softmax(f/g)
  float mq0 = 0.f, mq1 = 0.f, mq2 = 0.f, mq3 = 0.f;
  {
    float uval = U[ubase + (size_t)(T - 1) * ust];
    if (h == 0) b_sh[i] = uval;
    float fv = Fc[(size_t)(T - 1) * 32 + i];
    float mg = softmax32(fv * ig);
    if (dirV) { if (h == 0) MG[ubase + (size_t)(T - 1) * ust] = mg; }
    else mq3 = mg;   // (T-1)&3 == 3 since T % 4 == 0
  }
  int cur = 0;
  int c0 = i >> 3, il = i & 7;
  for (int ch = nch - 1; ch >= 0; ch--) {
    float4* dst = (float4*)(lds + (ch & 1) * 16384);
    #pragma unroll
    for (int q = 0; q < 16; q++) dst[q * 64 + tid] = stg[q];
    if (ch > 0) {
      const float4* s2 = src + (size_t)(ch - 1) * 1024;
      #pragma unroll
      for (int q = 0; q < 16; q++) stg[q] = s2[q * 64 + tid];
    }
    for (int ss = TC - 1; ss >= 0; ss--) {
      int s = ch * TC + ss;
      if (s >= Tt) continue;
      const uint16_t* sl16 = (const uint16_t*)(lds + (ch & 1) * 16384 + ss * 2048);
      float x[16];
      #pragma unroll
      for (int jj = 0; jj < 16; jj++) {
        int jq = h * 16 + jj;
        uint32_t u16v = sl16[jq * 32 + ((c0 ^ (jq & 3)) << 3) + il];
        x[jj] = __uint_as_float(u16v << 16);
      }
      float uval = U[ubase + (size_t)s * ust];
      float bnew = lse32(b_sh + cur * 32, h, x, igl2, gln2, uval);
      if (h == 0) b_sh[(cur ^ 1) * 32 + i] = bnew;
      cur ^= 1;
      float fv = Fc[(size_t)s * 32 + i];
      float mg = softmax32((fv + bnew - uval) * ig);
      if (dirV) {
        if (h == 0) MG[ubase + (size_t)s * ust] = mg;
      } else {
        int r = s & 3;
        if (r == 3) mq3 = mg; else if (r == 2) mq2 = mg; else if (r == 1) mq1 = mg;
        else {
          mq0 = mg;
          if (h == 0) *(float4*)(MG + ubase + s) = make_float4(mq0, mq1, mq2, mq3);
        }
      }
    }
  }
}

// ---------- combine: scatter-accumulate levels, write 4 output slabs ----------
__global__ __launch_bounds__(256) void k_combine(
    const float* __restrict__ uh0, const float* __restrict__ uv0,
    const float* __restrict__ MB, float* __restrict__ out)
{
  int idx = blockIdx.x * 256 + threadIdx.x;     // (b,c,y,x) over 2*32*128*128
  int x = idx & 127, y = (idx >> 7) & 127;
  int bc = idx >> 14;
  float mh0 = MB[idx];
  float mv0 = MB[1048576 + idx];
  int cnt = 1 + ((y & 1) << 1) + (x & 1);
  int coff = bc * 4096 + ((y >> 1) << 6) + (x >> 1);
  const float* cb = MB + 2097152 + (size_t)(cnt - 1) * 524288;
  float mhc = cb[coff];
  float mvc = cb[262144 + coff];
  float mha = mh0 + mhc, mva = mv0 + mvc;
  float avg = (mha + mva) * 0.25f;
  const float A = 0.0078125f;  // 1/128
  out[idx]           = uh0[idx] - A * (mh0 - avg);
  out[1048576 + idx] = uv0[idx] - A * (mv0 - avg);
  out[2097152 + idx] = mha;
  out[3145728 + idx] = mva;
}

extern "C" void kernel_launch(void* const* d_in, const int* in_sizes, int n_in,
                              void* d_out, int out_size, void* d_ws, size_t ws_size,
                              hipStream_t stream)
{
  (void)in_sizes; (void)n_in; (void)out_size; (void)ws_size;
  const float* gamma = (const float*)d_in[20];
  unsigned char* ws = (unsigned char*)d_ws;
  uint16_t* PT = (uint16_t*)ws;
  float* F = (float*)(ws + WS_OFF_F);
  float* MARG = (float*)(ws + WS_OFF_MARG);

  for (int lvl = 0; lvl < 5; lvl++) {
    int H = lvl ? 64 : 128;
    int W = H;
    const float* uh = (const float*)d_in[lvl * 4 + 0];
    const float* uv = (const float*)d_in[lvl * 4 + 1];
    const float* ph = (const float*)d_in[lvl * 4 + 2];
    const float* pv = (const float*)d_in[lvl * 4 + 3];
    float *mgh, *mgv;
    if (lvl == 0) { mgh = MARG; mgv = MARG + 1048576; }
    else { mgh = MARG + 2097152 + (size_t)(lvl - 1) * 524288; mgv = mgh + 262144; }

    { // horizontal chains: L=H rows, T=W
      int L = H, T = W, Tt = W - 1, Tpad = W;
      dim3 tg((unsigned)((Tt + 31) / 32), (unsigned)L, 2);
      k_transpose<<<tg, 256, 0, stream>>>(ph, PT, L, Tt, Tpad, /*fStride=*/Tt, /*Xtot=*/Tt, 0);
      k_fwd<<<2 * L, 64, 0, stream>>>(PT, uh, F, gamma, L, T, Tt, Tpad, 0);
      k_bwd<<<2 * L, 64, 0, stream>>>(PT, uh, F, mgh, gamma, L, T, Tt, Tpad, 0);
    }
    { // vertical chains: L=W cols, T=H
      int L = W, T = H, Tt = H - 1, Tpad = H;
      dim3 tg((unsigned)((L + 31) / 32), (unsigned)Tt, 2);
      k_transpose<<<tg, 256, 0, stream>>>(pv, PT, L, Tt, Tpad, /*fStride=*/L, /*Xtot=*/L, 1);
      k_fwd<<<2 * L, 64, 0, stream>>>(PT, uv, F, gamma, L, T, Tt, Tpad, 1);
      k_bwd<<<2 * L, 64, 0, stream>>>(PT, uv, F, mgv, gamma, L, T, Tt, Tpad, 1);
    }
  }
  k_combine<<<4096, 256, 0, stream>>>((const float*)d_in[0], (const float*)d_in[1],
                                      MARG, (float*)d_out);
}

// Round 2
// 1031.785 us; speedup vs baseline: 2.6040x; 2.6040x over previous
//
#include <hip/hip_runtime.h>
#include <stdint.h>

#define TC 4
#define CHUNK_BYTES (TC * 2048)          // 8192 B per chunk (4 t-slices)
#define LDS_DP (2 * CHUNK_BYTES + 256)

// ---------- helpers ----------
static __device__ __forceinline__ float lse32(const float* sh_prev, int h, const float* x,
                                              float igl2, float gln2, float uval)
{
  const float4* fp = (const float4*)(sh_prev + h * 16);
  float4 A = fp[0], B = fp[1], C = fp[2], D = fp[3];
  float v[16];
  v[0]=A.x+x[0];  v[1]=A.y+x[1];  v[2]=A.z+x[2];  v[3]=A.w+x[3];
  v[4]=B.x+x[4];  v[5]=B.y+x[5];  v[6]=B.z+x[6];  v[7]=B.w+x[7];
  v[8]=C.x+x[8];  v[9]=C.y+x[9];  v[10]=C.z+x[10];v[11]=C.w+x[11];
  v[12]=D.x+x[12];v[13]=D.y+x[13];v[14]=D.z+x[14];v[15]=D.w+x[15];
  float a0=fmaxf(v[0],v[8]), a1=fmaxf(v[1],v[9]), a2=fmaxf(v[2],v[10]), a3=fmaxf(v[3],v[11]);
  float a4=fmaxf(v[4],v[12]),a5=fmaxf(v[5],v[13]),a6=fmaxf(v[6],v[14]),a7=fmaxf(v[7],v[15]);
  float b0=fmaxf(a0,a4), b1=fmaxf(a1,a5), b2=fmaxf(a2,a6), b3=fmaxf(a3,a7);
  float m = fmaxf(fmaxf(b0,b1), fmaxf(b2,b3));
  float e0 = exp2f((v[0]-m)*igl2) + exp2f((v[1]-m)*igl2);
  float e1 = exp2f((v[2]-m)*igl2) + exp2f((v[3]-m)*igl2);
  float e2 = exp2f((v[4]-m)*igl2) + exp2f((v[5]-m)*igl2);
  float e3 = exp2f((v[6]-m)*igl2) + exp2f((v[7]-m)*igl2);
  float e4 = exp2f((v[8]-m)*igl2) + exp2f((v[9]-m)*igl2);
  float e5 = exp2f((v[10]-m)*igl2) + exp2f((v[11]-m)*igl2);
  float e6 = exp2f((v[12]-m)*igl2) + exp2f((v[13]-m)*igl2);
  float e7 = exp2f((v[14]-m)*igl2) + exp2f((v[15]-m)*igl2);
  float s = ((e0+e1)+(e2+e3)) + ((e4+e5)+(e6+e7));
  float mo = __shfl_xor(m, 32);
  float m2 = fmaxf(m, mo);
  float sadj = s * exp2f((m - m2) * igl2);
  float stot = sadj + __shfl_xor(sadj, 32);
  return uval + m2 + gln2 * __log2f(stot);
}

static __device__ __forceinline__ float softmax32(float z)
{
  float zm = z;
  zm = fmaxf(zm, __shfl_xor(zm, 16));
  zm = fmaxf(zm, __shfl_xor(zm, 8));
  zm = fmaxf(zm, __shfl_xor(zm, 4));
  zm = fmaxf(zm, __shfl_xor(zm, 2));
  zm = fmaxf(zm, __shfl_xor(zm, 1));
  float p = exp2f((z - zm) * 1.4426950408889634f);
  float ps = p;
  ps += __shfl_xor(ps, 16);
  ps += __shfl_xor(ps, 8);
  ps += __shfl_xor(ps, 4);
  ps += __shfl_xor(ps, 2);
  ps += __shfl_xor(ps, 1);
  return p / ps;
}

// ---------- descriptor tables ----------
struct TSeg { const float* pw; uint16_t* PT; int L, Tt, Tpad, fStride, Xtot, dirV, blockBase, nx, ny; };
struct TTable { TSeg s[10]; int nseg; };
struct USeg { const float* U; float* Ut; int fs, nx, ny, L, T, dirV, blockBase; };
struct UTable { USeg s[10]; int nseg; };
struct DSeg { const uint16_t* PT; const float* U; const float* Ut; float* F; float* MG;
              int chainBase, L, T, Tt, Tpad, dirV; };
struct DTable { DSeg s[10]; int nseg; };

// ---------- transpose: pw(f32) -> PT(bf16, [chain][t][j][i-xor-swizzled]) ----------
__global__ __launch_bounds__(256) void k_transpose_all(TTable tbl)
{
  __shared__ uint16_t tile[1024][33];
  int bid = blockIdx.x;
  int k = 0;
  for (int q = 1; q < tbl.nseg; q++) if (bid >= tbl.s[q].blockBase) k = q;
  TSeg sg = tbl.s[k];
  int r = bid - sg.blockBase;
  int bx = r % sg.nx; int tmp = r / sg.nx;
  int fixed = tmp % sg.ny;
  int b = tmp / sg.ny;
  int tid = threadIdx.x;
  int x0 = bx * 32;
  size_t bbase = (size_t)b * 1024 * sg.L * sg.Tt;
  int xx = tid & 31, ps = tid >> 5;
  int x = x0 + xx;
  bool xok = x < sg.Xtot;
  size_t rowoff = bbase + (size_t)fixed * sg.fStride + x;
  size_t pstride = (size_t)sg.L * sg.Tt;
  #pragma unroll 4
  for (int pg = 0; pg < 1024; pg += 8) {
    int p = pg + ps;
    float v = xok ? sg.pw[rowoff + (size_t)p * pstride] : 0.0f;
    uint32_t u = __float_as_uint(v);
    tile[p][xx] = (uint16_t)((u + 0x7FFFu + ((u >> 16) & 1u)) >> 16);  // RNE to bf16
  }
  __syncthreads();
  for (int w = 0; w < 64; w++) {
    int gidx = w * 256 + tid;       // 0..16383 : 32 slices * 512 dwords
    int xs = gidx >> 9;
    int d  = gidx & 511;
    int j   = d >> 4;
    int pos = (d >> 2) & 3;
    int dw  = d & 3;
    int c = pos ^ (j & 3);
    int i = c * 8 + dw * 2;
    uint32_t v0 = tile[i * 32 + j][xs];
    uint32_t v1 = tile[(i + 1) * 32 + j][xs];
    uint32_t pk = v0 | (v1 << 16);
    int xv = x0 + xs;
    if (xv >= sg.Xtot) continue;
    int chain, tsl;
    if (sg.dirV) { chain = b * sg.Xtot + xv; tsl = fixed; }
    else         { chain = b * sg.ny  + fixed; tsl = xv; }
    ((uint32_t*)sg.PT)[((size_t)chain * sg.Tpad + tsl) * 512 + d] = pk;
  }
}

// ---------- unary transpose: U[b,c,(plane)] -> Ut[chain][t][c] ----------
__global__ __launch_bounds__(256) void k_ut_all(UTable tbl)
{
  __shared__ float tile[32][33];
  int bid = blockIdx.x;
  int k = 0;
  for (int q = 1; q < tbl.nseg; q++) if (bid >= tbl.s[q].blockBase) k = q;
  USeg sg = tbl.s[k];
  int r = bid - sg.blockBase;
  int bx = r % sg.nx; int tmp = r / sg.nx;
  int fixed = tmp % sg.ny;
  int b = tmp / sg.ny;
  int tid = threadIdx.x;
  size_t LT = (size_t)sg.L * sg.T;
  int x0 = bx * 32;
  int xx = tid & 31;
  #pragma unroll
  for (int it = 0; it < 4; it++) {
    int c = (tid >> 5) + it * 8;
    tile[xx][c] = sg.U[(size_t)b * 32 * LT + (size_t)c * LT + (size_t)fixed * sg.fs + x0 + xx];
  }
  __syncthreads();
  int cw = tid & 31;
  #pragma unroll
  for (int it = 0; it < 4; it++) {
    int xw = (tid >> 5) + it * 8;
    int chain = sg.dirV ? b * sg.L + x0 + xw : b * sg.L + fixed;
    int tIdx  = sg.dirV ? fixed : x0 + xw;
    sg.Ut[((size_t)chain * sg.T + tIdx) * 32 + cw] = tile[xw][cw];
  }
}

// ---------- forward DP: one wave per chain ----------
__global__ __launch_bounds__(64) void k_fwd_all(DTable tbl, const float* __restrict__ gamma)
{
  __shared__ __align__(16) unsigned char lds[LDS_DP];
  float* f_sh = (float*)(lds + 2 * CHUNK_BYTES);
  int bid = blockIdx.x;
  int k = 0;
  for (int q = 1; q < tbl.nseg; q++) if (bid >= tbl.s[q].chainBase) k = q;
  DSeg sg = tbl.s[k];
  int chain = bid - sg.chainBase;
  int L = sg.L, T = sg.T, Tt = sg.Tt, Tpad = sg.Tpad;
  int b = chain / L, l = chain - b * L;
  int tid = threadIdx.x, j = tid & 31, h = tid >> 5;
  float g = fmaxf(gamma[0], 0.01f);
  float ig = 1.0f / g;
  float igl2 = ig * 1.4426950408889634f;
  float gln2 = g * 0.6931471805599453f;
  size_t LT = (size_t)L * T;
  size_t ubase = (size_t)b * 32 * LT + (size_t)l * (sg.dirV ? 1 : T) + (size_t)j * LT;
  int ust = sg.dirV ? L : 1;
  const float* Utc = sg.Ut ? sg.Ut + (size_t)chain * T * 32 : nullptr;
  float* Fc = sg.F + (size_t)chain * T * 32;
  float f0 = Utc ? Utc[j] : sg.U[ubase];
  if (h == 0) { f_sh[j] = f0; Fc[j] = f0; }
  const float4* src = (const float4*)(sg.PT + (size_t)chain * Tpad * 1024);
  int nch = Tpad / TC;
  float4 stg[TC * 2];
  #pragma unroll
  for (int q = 0; q < TC * 2; q++) stg[q] = src[q * 64 + tid];
  int cur = 0;
  for (int ch = 0; ch < nch; ch++) {
    float4* dst = (float4*)(lds + (ch & 1) * CHUNK_BYTES);
    #pragma unroll
    for (int q = 0; q < TC * 2; q++) dst[q * 64 + tid] = stg[q];
    if (ch + 1 < nch) {
      const float4* s2 = src + (size_t)(ch + 1) * (CHUNK_BYTES / 16);
      #pragma unroll
      for (int q = 0; q < TC * 2; q++) stg[q] = s2[q * 64 + tid];
    }
    int s0 = ch * TC;
    for (int ss = 0; ss < TC; ss++) {
      int s = s0 + ss;
      if (s >= Tt) break;
      const uint4* rowp = (const uint4*)(lds + (ch & 1) * CHUNK_BYTES + ss * 2048 + j * 64);
      uint4 r0 = rowp[(2 * h) ^ (j & 3)];
      uint4 r1 = rowp[(2 * h + 1) ^ (j & 3)];
      float x[16];
      x[0]=__uint_as_float(r0.x<<16); x[1]=__uint_as_float(r0.x&0xFFFF0000u);
      x[2]=__uint_as_float(r0.y<<16); x[3]=__uint_as_float(r0.y&0xFFFF0000u);
      x[4]=__uint_as_float(r0.z<<16); x[5]=__uint_as_float(r0.z&0xFFFF0000u);
      x[6]=__uint_as_float(r0.w<<16); x[7]=__uint_as_float(r0.w&0xFFFF0000u);
      x[8]=__uint_as_float(r1.x<<16); x[9]=__uint_as_float(r1.x&0xFFFF0000u);
      x[10]=__uint_as_float(r1.y<<16);x[11]=__uint_as_float(r1.y&0xFFFF0000u);
      x[12]=__uint_as_float(r1.z<<16);x[13]=__uint_as_float(r1.z&0xFFFF0000u);
      x[14]=__uint_as_float(r1.w<<16);x[15]=__uint_as_float(r1.w&0xFFFF0000u);
      int t = s + 1;
      float uval = Utc ? Utc[(size_t)t * 32 + j] : sg.U[ubase + (size_t)t * ust];
      float fnew = lse32(f_sh + cur * 32, h, x, igl2, gln2, uval);
      if (h == 0) { f_sh[(cur ^ 1) * 32 + j] = fnew; Fc[(size_t)t * 32 + j] = fnew; }
      cur ^= 1;
    }
  }
}

// ---------- backward DP + fused marginals ----------
__global__ __launch_bounds__(64) void k_bwd_all(DTable tbl, const float* __restrict__ gamma)
{
  __shared__ __align__(16) unsigned char lds[LDS_DP];
  float* b_sh = (float*)(lds + 2 * CHUNK_BYTES);
  int bid = blockIdx.x;
  int k = 0;
  for (int q = 1; q < tbl.nseg; q++) if (bid >= tbl.s[q].chainBase) k = q;
  DSeg sg = tbl.s[k];
  int chain = bid - sg.chainBase;
  int L = sg.L, T = sg.T, Tt = sg.Tt, Tpad = sg.Tpad;
  int b = chain / L, l = chain - b * L;
  int tid = threadIdx.x, i = tid & 31, h = tid >> 5;
  float g = fmaxf(gamma[0], 0.01f);
  float ig = 1.0f / g;
  float igl2 = ig * 1.4426950408889634f;
  float gln2 = g * 0.6931471805599453f;
  size_t LT = (size_t)L * T;
  size_t ubase = (size_t)b * 32 * LT + (size_t)l * (sg.dirV ? 1 : T) + (size_t)i * LT;
  int ust = sg.dirV ? L : 1;
  const float* Utc = sg.Ut ? sg.Ut + (size_t)chain * T * 32 : nullptr;
  const float* Fc = sg.F + (size_t)chain * T * 32;
  float* MG = sg.MG;
  const float4* src = (const float4*)(sg.PT + (size_t)chain * Tpad * 1024);
  int nch = Tpad / TC;
  float4 stg[TC * 2];
  {
    const float4* s2 = src + (size_t)(nch - 1) * (CHUNK_BYTES / 16);
    #pragma unroll
    for (int q = 0; q < TC * 2; q++) stg[q] = s2[q * 64 + tid];
  }
  // prologue t = T-1 : b = u, marg = softmax(f/g)
  float mq0 = 0.f, mq1 = 0.f, mq2 = 0.f, mq3 = 0.f;
  {
    float uval = Utc ? Utc[(size_t)(T - 1) * 32 + i] : sg.U[ubase + (size_t)(T - 1) * ust];
    if (h == 0) b_sh[i] = uval;
    float fv = Fc[(size_t)(T - 1) * 32 + i];
    float mg = softmax32(fv * ig);
    if (sg.dirV) { if (h == 0) MG[ubase + (size_t)(T - 1) * ust] = mg; }
    else mq3 = mg;   // (T-1)&3 == 3 since T % 4 == 0
  }
  int cur = 0;
  int c0 = i >> 3, il = i & 7;
  for (int ch = nch - 1; ch >= 0; ch--) {
    float4* dst = (float4*)(lds + (ch & 1) * CHUNK_BYTES);
    #pragma unroll
    for (int q = 0; q < TC * 2; q++) dst[q * 64 + tid] = stg[q];
    if (ch > 0) {
      const float4* s2 = src + (size_t)(ch - 1) * (CHUNK_BYTES / 16);
      #pragma unroll
      for (int q = 0; q < TC * 2; q++) stg[q] = s2[q * 64 + tid];
    }
    for (int ss = TC - 1; ss >= 0; ss--) {
      int s = ch * TC + ss;
      if (s >= Tt) continue;
      const uint16_t* sl16 = (const uint16_t*)(lds + (ch & 1) * CHUNK_BYTES + ss * 2048);
      float x[16];
      #pragma unroll
      for (int jj = 0; jj < 16; jj++) {
        int jq = h * 16 + jj;
        uint32_t u16v = sl16[jq * 32 + ((c0 ^ (jq & 3)) << 3) + il];
        x[jj] = __uint_as_float(u16v << 16);
      }
      float uval = Utc ? Utc[(size_t)s * 32 + i] : sg.U[ubase + (size_t)s * ust];
      float bnew = lse32(b_sh + cur * 32, h, x, igl2, gln2, uval);
      if (h == 0) b_sh[(cur ^ 1) * 32 + i] = bnew;
      cur ^= 1;
      float fv = Fc[(size_t)s * 32 + i];
      float mg = softmax32((fv + bnew - uval) * ig);
      if (sg.dirV) {
        if (h == 0) MG[ubase + (size_t)s * ust] = mg;
      } else {
        int r = s & 3;
        if (r == 3) mq3 = mg; else if (r == 2) mq2 = mg; else if (r == 1) mq1 = mg;
        else {
          mq0 = mg;
          if (h == 0) *(float4*)(MG + ubase + s) = make_float4(mq0, mq1, mq2, mq3);
        }
      }
    }
  }
}

// ---------- combine: scatter-accumulate levels, write 4 output slabs ----------
__global__ __launch_bounds__(256) void k_combine(
    const float* __restrict__ uh0, const float* __restrict__ uv0,
    const float* __restrict__ MB, float* __restrict__ out)
{
  int idx = blockIdx.x * 256 + threadIdx.x;     // (b,c,y,x) over 2*32*128*128
  int x = idx & 127, y = (idx >> 7) & 127;
  int bc = idx >> 14;
  float mh0 = MB[idx];
  float mv0 = MB[1048576 + idx];
  int cnt = 1 + ((y & 1) << 1) + (x & 1);
  int coff = bc * 4096 + ((y >> 1) << 6) + (x >> 1);
  const float* cb = MB + 2097152 + (size_t)(cnt - 1) * 524288;
  float mhc = cb[coff];
  float mvc = cb[262144 + coff];
  float mha = mh0 + mhc, mva = mv0 + mvc;
  float avg = (mha + mva) * 0.25f;
  const float A = 0.0078125f;  // 1/128
  out[idx]           = uh0[idx] - A * (mh0 - avg);
  out[1048576 + idx] = uv0[idx] - A * (mv0 - avg);
  out[2097152 + idx] = mha;
  out[3145728 + idx] = mva;
}

// ---------- launch ----------
static void fill_tseg(TSeg& t, const float* pw, uint16_t* PT, int L, int T, int dirV, int blockBase)
{
  int Tt = T - 1;
  t.pw = pw; t.PT = PT;
  t.L = L; t.Tt = Tt; t.Tpad = T;
  t.fStride = dirV ? L : Tt;
  t.Xtot = dirV ? L : Tt;
  t.dirV = dirV;
  t.nx = (t.Xtot + 31) / 32;
  t.ny = dirV ? Tt : L;
  t.blockBase = blockBase;
}

extern "C" void kernel_launch(void* const* d_in, const int* in_sizes, int n_in,
                              void* d_out, int out_size, void* d_ws, size_t ws_size,
                              hipStream_t stream)
{
  (void)in_sizes; (void)n_in; (void)out_size;
  const float* gamma = (const float*)d_in[20];
  unsigned char* ws = (unsigned char*)d_ws;

  // segment geometry: order lvl0h, lvl0v, lvl1h, lvl1v, ...
  int segL[10], segT[10];
  const float* segPW[10]; const float* segUU[10];
  size_t segMG[10];
  for (int lvl = 0; lvl < 5; lvl++) {
    int H = lvl ? 64 : 128, W = H;
    int si = lvl * 2;
    segL[si] = H; segT[si] = W;               // horizontal: chains along rows
    segPW[si] = (const float*)d_in[lvl * 4 + 2];
    segUU[si] = (const float*)d_in[lvl * 4 + 0];
    segL[si + 1] = W; segT[si + 1] = H;       // vertical: chains along cols
    segPW[si + 1] = (const float*)d_in[lvl * 4 + 3];
    segUU[si + 1] = (const float*)d_in[lvl * 4 + 1];
    if (lvl == 0) { segMG[0] = 0; segMG[1] = 1048576; }
    else { segMG[si] = 2097152 + (size_t)(lvl - 1) * 524288; segMG[si + 1] = segMG[si] + 262144; }
  }

  const size_t NEED = 318767104ull;  // PT 256MiB + F 16MiB + Ut 16MiB + MARG 16MiB
  if (ws_size >= NEED) {
    uint16_t* PT0 = (uint16_t*)ws;
    float* F0   = (float*)(ws + 268435456ull);
    float* Ut0  = (float*)(ws + 285212672ull);
    float* MARG = (float*)(ws + 301989888ull);

    TTable tt; UTable ut; DTable dt;
    tt.nseg = 10; ut.nseg = 10; dt.nseg = 10;
    size_t ptOff = 0, fuOff = 0;
    int tB = 0, uB = 0, cB = 0;
    for (int s = 0; s < 10; s++) {
      int dirV = s & 1;
      int L = segL[s], T = segT[s];
      int chains = 2 * L;
      fill_tseg(tt.s[s], segPW[s], PT0 + ptOff, L, T, dirV, tB);
      tB += tt.s[s].nx * tt.s[s].ny * 2;
      USeg& u = ut.s[s];
      u.U = segUU[s]; u.Ut = Ut0 + fuOff;
      u.fs = dirV ? L : T;
      u.nx = (dirV ? L : T) / 32;
      u.ny = dirV ? T : L;
      u.L = L; u.T = T; u.dirV = dirV;
      u.blockBase = uB;
      uB += u.nx * u.ny * 2;
      DSeg& d = dt.s[s];
      d.PT = PT0 + ptOff; d.U = segUU[s]; d.Ut = Ut0 + fuOff;
      d.F = F0 + fuOff; d.MG = MARG + segMG[s];
      d.chainBase = cB; d.L = L; d.T = T; d.Tt = T - 1; d.Tpad = T; d.dirV = dirV;
      cB += chains;
      ptOff += (size_t)chains * T * 1024;
      fuOff += (size_t)chains * T * 32;
    }
    k_transpose_all<<<tB, 256, 0, stream>>>(tt);
    k_ut_all<<<uB, 256, 0, stream>>>(ut);
    k_fwd_all<<<cB, 64, 0, stream>>>(dt, gamma);
    k_bwd_all<<<cB, 64, 0, stream>>>(dt, gamma);
    k_combine<<<4096, 256, 0, stream>>>((const float*)d_in[0], (const float*)d_in[1],
                                        MARG, (float*)d_out);
  } else {
    // level-serial fallback (proven path, shared PT/F regions, no Ut)
    uint16_t* PT0 = (uint16_t*)ws;
    float* F0   = (float*)(ws + 67108864ull);
    float* MARG = (float*)(ws + 71303168ull);
    for (int s = 0; s < 10; s++) {
      int dirV = s & 1;
      int L = segL[s], T = segT[s];
      int chains = 2 * L;
      TTable tt; tt.nseg = 1;
      fill_tseg(tt.s[0], segPW[s], PT0, L, T, dirV, 0);
      int nb = tt.s[0].nx * tt.s[0].ny * 2;
      k_transpose_all<<<nb, 256, 0, stream>>>(tt);
      DTable dt; dt.nseg = 1;
      DSeg& d = dt.s[0];
      d.PT = PT0; d.U = segUU[s]; d.Ut = nullptr;
      d.F = F0; d.MG = MARG + segMG[s];
      d.chainBase = 0; d.L = L; d.T = T; d.Tt = T - 1; d.Tpad = T; d.dirV = dirV;
      k_fwd_all<<<chains, 64, 0, stream>>>(dt, gamma);
      k_bwd_all<<<chains, 64, 0, stream>>>(dt, gamma);
    }
    k_combine<<<4096, 256, 0, stream>>>((const float*)d_in[0], (const float*)d_in[1],
                                        MARG, (float*)d_out);
  }
}

// Round 3
// 811.957 us; speedup vs baseline: 3.3090x; 1.2707x over previous
//
#include <hip/hip_runtime.h>
#include <stdint.h>

#define TC 4
#define CHUNK_BYTES 8192
#define CHUNK_F4 512

// ---------- helpers ----------
static __device__ __forceinline__ float lse16x2(const float* v, float igl2, float gln2, float uval)
{
  float a0=fmaxf(v[0],v[8]), a1=fmaxf(v[1],v[9]), a2=fmaxf(v[2],v[10]), a3=fmaxf(v[3],v[11]);
  float a4=fmaxf(v[4],v[12]),a5=fmaxf(v[5],v[13]),a6=fmaxf(v[6],v[14]),a7=fmaxf(v[7],v[15]);
  float b0=fmaxf(a0,a4), b1=fmaxf(a1,a5), b2=fmaxf(a2,a6), b3=fmaxf(a3,a7);
  float m = fmaxf(fmaxf(b0,b1), fmaxf(b2,b3));
  float e0 = exp2f((v[0]-m)*igl2) + exp2f((v[1]-m)*igl2);
  float e1 = exp2f((v[2]-m)*igl2) + exp2f((v[3]-m)*igl2);
  float e2 = exp2f((v[4]-m)*igl2) + exp2f((v[5]-m)*igl2);
  float e3 = exp2f((v[6]-m)*igl2) + exp2f((v[7]-m)*igl2);
  float e4 = exp2f((v[8]-m)*igl2) + exp2f((v[9]-m)*igl2);
  float e5 = exp2f((v[10]-m)*igl2) + exp2f((v[11]-m)*igl2);
  float e6 = exp2f((v[12]-m)*igl2) + exp2f((v[13]-m)*igl2);
  float e7 = exp2f((v[14]-m)*igl2) + exp2f((v[15]-m)*igl2);
  float s = ((e0+e1)+(e2+e3)) + ((e4+e5)+(e6+e7));
  float mo = __shfl_xor(m, 32);
  float m2 = fmaxf(m, mo);
  float sadj = s * exp2f((m - m2) * igl2);
  float stot = sadj + __shfl_xor(sadj, 32);
  return uval + m2 + gln2 * __log2f(stot);
}

static __device__ __forceinline__ float softmax32(float z)
{
  float zm = z;
  zm = fmaxf(zm, __shfl_xor(zm, 16));
  zm = fmaxf(zm, __shfl_xor(zm, 8));
  zm = fmaxf(zm, __shfl_xor(zm, 4));
  zm = fmaxf(zm, __shfl_xor(zm, 2));
  zm = fmaxf(zm, __shfl_xor(zm, 1));
  float p = exp2f((z - zm) * 1.4426950408889634f);
  float ps = p;
  ps += __shfl_xor(ps, 16);
  ps += __shfl_xor(ps, 8);
  ps += __shfl_xor(ps, 4);
  ps += __shfl_xor(ps, 2);
  ps += __shfl_xor(ps, 1);
  return p / ps;
}

// ---------- descriptor tables ----------
struct TSeg { const float* pw; uint16_t* PT; int L, Tt, Tpad, fStride, Xtot, dirV, blockBase, nx, ny; };
struct TTable { TSeg s[10]; int nseg; };
struct USeg { const float* U; float* Ut; int fs, nx, ny, L, T, dirV, blockBase; };
struct UTable { USeg s[10]; int nseg; };
struct DSeg { const uint16_t* PT; const float* Ut; float* F; float* B; int chainBase, T, Tt, Tpad; };
struct DTable { DSeg s[10]; int nseg; };
struct MSeg { const float* F; const float* B; const float* Ut; float* out; int L, T, dirV, blockBase, nrx, nfx; };
struct MTable { MSeg s[10]; int nseg; };

// ---------- transpose: pw(f32) -> PT(bf16, slice layout d = j*16 + (p2^((j>>1)&7))*2 + pr) ----------
__global__ __launch_bounds__(256) void k_transpose_all(TTable tbl)
{
  __shared__ uint16_t tile[1024][32];    // col-swizzled at dword granularity
  int bid = blockIdx.x;
  int k = 0;
  for (int q = 1; q < tbl.nseg; q++) if (bid >= tbl.s[q].blockBase) k = q;
  TSeg sg = tbl.s[k];
  int r = bid - sg.blockBase;
  int bx = r % sg.nx; int tmp = r / sg.nx;
  int fixed = tmp % sg.ny;
  int b = tmp / sg.ny;
  int tid = threadIdx.x;
  int x0 = bx * 32;
  size_t bbase = (size_t)b * 1024 * sg.L * sg.Tt;
  int xx = tid & 31, ps = tid >> 5;
  int x = x0 + xx;
  bool xok = x < sg.Xtot;
  size_t rowoff = bbase + (size_t)fixed * sg.fStride + x;
  size_t pstride = (size_t)sg.L * sg.Tt;
  #pragma unroll 4
  for (int pg = 0; pg < 1024; pg += 8) {
    int p = pg + ps;
    float v = xok ? sg.pw[rowoff + (size_t)p * pstride] : 0.0f;
    uint32_t u = __float_as_uint(v);
    uint16_t bf = (uint16_t)((u + 0x7FFFu + ((u >> 16) & 1u)) >> 16);  // RNE to bf16
    int sw = ((p >> 1) & 3) ^ (((p >> 8) & 3) << 2);   // j bits 1-2 ^ (i>>3)<<2
    tile[p][2 * (((xx >> 1) ^ sw) & 15) + (xx & 1)] = bf;
  }
  __syncthreads();
  uint32_t* PTd = (uint32_t*)sg.PT;
  for (int w = 0; w < 16; w++) {
    int gidx = w * 256 + tid;        // quad id: 32 slices * 128 quads
    int xs = gidx >> 7;
    int qd = gidx & 127;
    int j = qd >> 2;
    int perm3 = (j >> 1) & 7;
    uint32_t pk[4];
    #pragma unroll
    for (int e = 0; e < 4; e++) {
      int ww = (qd & 3) * 4 + e;          // dword-in-row 0..15
      int pos = ww >> 1, pr = ww & 1;
      int i0 = ((pos ^ perm3) << 2) + pr * 2;
      int sw0 = ((j >> 1) & 3) ^ (((i0 >> 3) & 3) << 2);
      int col = 2 * (((xs >> 1) ^ sw0) & 15) + (xs & 1);
      uint32_t v0 = tile[i0 * 32 + j][col];
      uint32_t v1 = tile[(i0 + 1) * 32 + j][col];
      pk[e] = v0 | (v1 << 16);
    }
    int xv = x0 + xs;
    if (xv >= sg.Xtot) continue;
    int chain, tsl;
    if (sg.dirV) { chain = b * sg.Xtot + xv; tsl = fixed; }
    else         { chain = b * sg.ny + fixed; tsl = xv; }
    *(uint4*)&PTd[((size_t)chain * sg.Tpad + tsl) * 512 + qd * 4] =
        make_uint4(pk[0], pk[1], pk[2], pk[3]);
  }
}

// ---------- unary transpose: U[b,c,(plane)] -> Ut[chain][t][c] ----------
__global__ __launch_bounds__(256) void k_ut_all(UTable tbl)
{
  __shared__ float tile[32][33];
  int bid = blockIdx.x;
  int k = 0;
  for (int q = 1; q < tbl.nseg; q++) if (bid >= tbl.s[q].blockBase) k = q;
  USeg sg = tbl.s[k];
  int r = bid - sg.blockBase;
  int bx = r % sg.nx; int tmp = r / sg.nx;
  int fixed = tmp % sg.ny;
  int b = tmp / sg.ny;
  int tid = threadIdx.x;
  size_t LT = (size_t)sg.L * sg.T;
  int x0 = bx * 32;
  int xx = tid & 31;
  #pragma unroll
  for (int it = 0; it < 4; it++) {
    int c = (tid >> 5) + it * 8;
    tile[xx][c] = sg.U[(size_t)b * 32 * LT + (size_t)c * LT + (size_t)fixed * sg.fs + x0 + xx];
  }
  __syncthreads();
  int cw = tid & 31;
  #pragma unroll
  for (int it = 0; it < 4; it++) {
    int xw = (tid >> 5) + it * 8;
    int chain = sg.dirV ? b * sg.L + x0 + xw : b * sg.L + fixed;
    int tIdx  = sg.dirV ? fixed : x0 + xw;
    sg.Ut[((size_t)chain * sg.T + tIdx) * 32 + cw] = tile[xw][cw];
  }
}

// ---------- DP: fwd and bwd chains concurrently; one wave per chain ----------
__global__ __launch_bounds__(64) void k_dp_all(DTable tbl, const float* __restrict__ gamma, int nDP)
{
  __shared__ __align__(16) unsigned char lds[2 * CHUNK_BYTES];
  int bid = blockIdx.x;
  int isB = (bid >= nDP) ? 1 : 0;
  bid -= isB * nDP;
  int k = 0;
  for (int q = 1; q < tbl.nseg; q++) if (bid >= tbl.s[q].chainBase) k = q;
  DSeg sg = tbl.s[k];
  int chain = bid - sg.chainBase;
  int T = sg.T, Tt = sg.Tt;
  int tid = threadIdx.x, j = tid & 31, h = tid >> 5;
  float g = fmaxf(gamma[0], 0.01f);
  float igl2 = (1.0f / g) * 1.4426950408889634f;
  float gln2 = g * 0.6931471805599453f;
  const float* Utc = sg.Ut + (size_t)chain * T * 32;
  float* Oc = (isB ? sg.B : sg.F) + (size_t)chain * T * 32;
  const float4* src = (const float4*)(sg.PT + (size_t)chain * sg.Tpad * 1024);
  int nch = sg.Tpad / TC;
  int perm3 = (j >> 1) & 7;
  int gbase = h * 48;
  float4 stg[8];
  if (!isB) {
    float cur = Utc[j];
    if (h == 0) Oc[j] = cur;
    #pragma unroll
    for (int q = 0; q < 8; q++) stg[q] = src[q * 64 + tid];
    int buf = 0;
    for (int ch = 0; ch < nch; ch++) {
      float4* dst = (float4*)(lds + buf * CHUNK_BYTES);
      #pragma unroll
      for (int q = 0; q < 8; q++) dst[q * 64 + tid] = stg[q];
      if (ch + 1 < nch) {
        const float4* s2 = src + (size_t)(ch + 1) * CHUNK_F4;
        #pragma unroll
        for (int q = 0; q < 8; q++) stg[q] = s2[q * 64 + tid];
      }
      #pragma unroll
      for (int ss = 0; ss < TC; ss++) {
        int s = ch * TC + ss;
        if (s >= Tt) break;
        const uint32_t* sl = (const uint32_t*)(lds + buf * CHUNK_BYTES + ss * 2048);
        float v[16];
        #pragma unroll
        for (int rr = 0; rr < 4; rr++) {
          int pos = (4 * h + rr) ^ perm3;
          uint2 dv = *(const uint2*)&sl[j * 16 + pos * 2];
          v[rr * 4 + 0] = __uint_as_float(dv.x << 16);
          v[rr * 4 + 1] = __uint_as_float(dv.x & 0xFFFF0000u);
          v[rr * 4 + 2] = __uint_as_float(dv.y << 16);
          v[rr * 4 + 3] = __uint_as_float(dv.y & 0xFFFF0000u);
        }
        #pragma unroll
        for (int q = 0; q < 16; q++) v[q] += __shfl(cur, gbase + q);
        float uval = Utc[(size_t)(s + 1) * 32 + j];
        cur = lse16x2(v, igl2, gln2, uval);
        if (h == 0) Oc[(size_t)(s + 1) * 32 + j] = cur;
      }
      buf ^= 1;
    }
  } else {
    int p2i = j >> 2, pri = (j >> 1) & 1, loi = j & 1;
    float cur = Utc[(size_t)(T - 1) * 32 + j];
    if (h == 0) Oc[(size_t)(T - 1) * 32 + j] = cur;
    {
      const float4* s2 = src + (size_t)(nch - 1) * CHUNK_F4;
      #pragma unroll
      for (int q = 0; q < 8; q++) stg[q] = s2[q * 64 + tid];
    }
    int buf = 0;
    for (int ch = nch - 1; ch >= 0; ch--) {
      float4* dst = (float4*)(lds + buf * CHUNK_BYTES);
      #pragma unroll
      for (int q = 0; q < 8; q++) dst[q * 64 + tid] = stg[q];
      if (ch > 0) {
        const float4* s2 = src + (size_t)(ch - 1) * CHUNK_F4;
        #pragma unroll
        for (int q = 0; q < 8; q++) stg[q] = s2[q * 64 + tid];
      }
      #pragma unroll
      for (int ss = TC - 1; ss >= 0; ss--) {
        int s = ch * TC + ss;
        if (s >= Tt) continue;
        const uint16_t* row16 = (const uint16_t*)(lds + buf * CHUNK_BYTES + ss * 2048);
        float v[16];
        #pragma unroll
        for (int jj = 0; jj < 16; jj++) {
          int u16idx = (16 * h + jj) * 32 + ((p2i ^ (jj >> 1)) * 2 + pri) * 2 + loi;
          v[jj] = __uint_as_float((uint32_t)row16[u16idx] << 16);
        }
        #pragma unroll
        for (int q = 0; q < 16; q++) v[q] += __shfl(cur, gbase + q);
        float uval = Utc[(size_t)s * 32 + j];
        cur = lse16x2(v, igl2, gln2, uval);
        if (h == 0) Oc[(size_t)s * 32 + j] = cur;
      }
      buf ^= 1;
    }
  }
}

// ---------- marginals: softmax((F+B-Ut)/g) over c, LDS-transposed coalesced write ----------
__global__ __launch_bounds__(256) void k_marg_all(MTable tbl, const float* __restrict__ gamma)
{
  __shared__ float sm[32][33];
  int bid = blockIdx.x;
  int k = 0;
  for (int q = 1; q < tbl.nseg; q++) if (bid >= tbl.s[q].blockBase) k = q;
  MSeg sg = tbl.s[k];
  int r = bid - sg.blockBase;
  int rx = r % sg.nrx; int tmp = r / sg.nrx;
  int fx = tmp % sg.nfx; int b = tmp / sg.nfx;
  int tid = threadIdx.x;
  float g = fmaxf(gamma[0], 0.01f);
  float ig = 1.0f / g;
  int c = tid & 31;
  int L = sg.L, T = sg.T;
  size_t LT = (size_t)L * T;
  int RA = sg.dirV ? L : T;
  int r0 = rx * 32;
  #pragma unroll
  for (int pass = 0; pass < 4; pass++) {
    int rr = (tid >> 5) + pass * 8;
    int rowAxis = r0 + rr;
    int chain = sg.dirV ? b * L + rowAxis : b * L + fx;
    int t = sg.dirV ? fx : rowAxis;
    size_t idx = ((size_t)chain * T + t) * 32 + c;
    float z = (sg.F[idx] + sg.B[idx] - sg.Ut[idx]) * ig;
    sm[rr][c] = softmax32(z);
  }
  __syncthreads();
  size_t obase = (size_t)b * 32 * LT + (size_t)fx * RA + r0;
  #pragma unroll
  for (int pass = 0; pass < 4; pass++) {
    int cc = (tid >> 5) + pass * 8;
    sg.out[obase + (size_t)cc * LT + (tid & 31)] = sm[tid & 31][cc];
  }
}

// ---------- combine ----------
__global__ __launch_bounds__(256) void k_combine(
    const float* __restrict__ uh0, const float* __restrict__ uv0,
    const float* __restrict__ MB, float* __restrict__ out)
{
  int idx = blockIdx.x * 256 + threadIdx.x;
  int x = idx & 127, y = (idx >> 7) & 127;
  int bc = idx >> 14;
  float mh0 = MB[idx];
  float mv0 = MB[1048576 + idx];
  int cnt = 1 + ((y & 1) << 1) + (x & 1);
  int coff = bc * 4096 + ((y >> 1) << 6) + (x >> 1);
  const float* cb = MB + 2097152 + (size_t)(cnt - 1) * 524288;
  float mhc = cb[coff];
  float mvc = cb[262144 + coff];
  float mha = mh0 + mhc, mva = mv0 + mvc;
  float avg = (mha + mva) * 0.25f;
  const float A = 0.0078125f;
  out[idx]           = uh0[idx] - A * (mh0 - avg);
  out[1048576 + idx] = uv0[idx] - A * (mv0 - avg);
  out[2097152 + idx] = mha;
  out[3145728 + idx] = mva;
}

// ---------- launch ----------
static void fill_tseg(TSeg& t, const float* pw, uint16_t* PT, int L, int T, int dirV, int blockBase)
{
  int Tt = T - 1;
  t.pw = pw; t.PT = PT;
  t.L = L; t.Tt = Tt; t.Tpad = T;
  t.fStride = dirV ? L : Tt;
  t.Xtot = dirV ? L : Tt;
  t.dirV = dirV;
  t.nx = (t.Xtot + 31) / 32;
  t.ny = dirV ? Tt : L;
  t.blockBase = blockBase;
}

extern "C" void kernel_launch(void* const* d_in, const int* in_sizes, int n_in,
                              void* d_out, int out_size, void* d_ws, size_t ws_size,
                              hipStream_t stream)
{
  (void)in_sizes; (void)n_in; (void)out_size;
  const float* gamma = (const float*)d_in[20];
  unsigned char* ws = (unsigned char*)d_ws;

  int segL[10], segT[10];
  const float* segPW[10]; const float* segUU[10];
  size_t segMG[10];
  for (int lvl = 0; lvl < 5; lvl++) {
    int H = lvl ? 64 : 128, W = H;
    int si = lvl * 2;
    segL[si] = H; segT[si] = W;
    segPW[si] = (const float*)d_in[lvl * 4 + 2];
    segUU[si] = (const float*)d_in[lvl * 4 + 0];
    segL[si + 1] = W; segT[si + 1] = H;
    segPW[si + 1] = (const float*)d_in[lvl * 4 + 3];
    segUU[si + 1] = (const float*)d_in[lvl * 4 + 1];
    if (lvl == 0) { segMG[0] = 0; segMG[1] = 1048576; }
    else { segMG[si] = 2097152 + (size_t)(lvl - 1) * 524288; segMG[si + 1] = segMG[si] + 262144; }
  }

  const size_t NEED = 318767104ull;  // PT 256MiB (MARG aliased) + F/B/Ut 16MiB each
  if (ws_size >= NEED) {
    uint16_t* PT0 = (uint16_t*)ws;
    float* MARG = (float*)ws;                       // aliased over PT, used after DP
    float* F0  = (float*)(ws + 268435456ull);
    float* B0  = (float*)(ws + 285212672ull);
    float* Ut0 = (float*)(ws + 301989888ull);

    TTable tt; UTable ut; DTable dt; MTable mt;
    tt.nseg = 10; ut.nseg = 10; dt.nseg = 10; mt.nseg = 10;
    size_t ptOff = 0, fuOff = 0;
    int tB = 0, uB = 0, cB = 0, mB = 0;
    for (int s = 0; s < 10; s++) {
      int dirV = s & 1;
      int L = segL[s], T = segT[s];
      int chains = 2 * L;
      fill_tseg(tt.s[s], segPW[s], PT0 + ptOff, L, T, dirV, tB);
      tB += tt.s[s].nx * tt.s[s].ny * 2;
      USeg& u = ut.s[s];
      u.U = segUU[s]; u.Ut = Ut0 + fuOff;
      u.fs = dirV ? L : T;
      u.nx = (dirV ? L : T) / 32;
      u.ny = dirV ? T : L;
      u.L = L; u.T = T; u.dirV = dirV;
      u.blockBase = uB;
      uB += u.nx * u.ny * 2;
      DSeg& d = dt.s[s];
      d.PT = PT0 + ptOff; d.Ut = Ut0 + fuOff;
      d.F = F0 + fuOff; d.B = B0 + fuOff;
      d.chainBase = cB; d.T = T; d.Tt = T - 1; d.Tpad = T;
      cB += chains;
      MSeg& m = mt.s[s];
      m.F = F0 + fuOff; m.B = B0 + fuOff; m.Ut = Ut0 + fuOff;
      m.out = MARG + segMG[s];
      m.L = L; m.T = T; m.dirV = dirV;
      m.blockBase = mB;
      m.nrx = (dirV ? L : T) / 32;
      m.nfx = dirV ? T : L;
      mB += 2 * m.nfx * m.nrx;
      ptOff += (size_t)chains * T * 1024;
      fuOff += (size_t)chains * T * 32;
    }
    k_transpose_all<<<tB, 256, 0, stream>>>(tt);
    k_ut_all<<<uB, 256, 0, stream>>>(ut);
    k_dp_all<<<2 * cB, 64, 0, stream>>>(dt, gamma, cB);
    k_marg_all<<<mB, 256, 0, stream>>>(mt, gamma);
    k_combine<<<4096, 256, 0, stream>>>((const float*)d_in[0], (const float*)d_in[1],
                                        MARG, (float*)d_out);
  } else {
    // level-serial fallback: PT@0 (64MiB), F@64Mi, B@68Mi, Ut@72Mi... MARG separate
    uint16_t* PT0 = (uint16_t*)ws;
    float* F0  = (float*)(ws + 67108864ull);
    float* B0  = (float*)(ws + 71303168ull);
    float* Ut0 = (float*)(ws + 75497472ull);
    float* MARG = (float*)(ws + 79691776ull);
    for (int s = 0; s < 10; s++) {
      int dirV = s & 1;
      int L = segL[s], T = segT[s];
      int chains = 2 * L;
      TTable tt; tt.nseg = 1;
      fill_tseg(tt.s[0], segPW[s], PT0, L, T, dirV, 0);
      int nb = tt.s[0].nx * tt.s[0].ny * 2;
      k_transpose_all<<<nb, 256, 0, stream>>>(tt);
      UTable ut; ut.nseg = 1;
      USeg& u = ut.s[0];
      u.U = segUU[s]; u.Ut = Ut0;
      u.fs = dirV ? L : T;
      u.nx = (dirV ? L : T) / 32;
      u.ny = dirV ? T : L;
      u.L = L; u.T = T; u.dirV = dirV; u.blockBase = 0;
      int ub = u.nx * u.ny * 2;
      k_ut_all<<<ub, 256, 0, stream>>>(ut);
      DTable dt; dt.nseg = 1;
      DSeg& d = dt.s[0];
      d.PT = PT0; d.Ut = Ut0; d.F = F0; d.B = B0;
      d.chainBase = 0; d.T = T; d.Tt = T - 1; d.Tpad = T;
      k_dp_all<<<2 * chains, 64, 0, stream>>>(dt, gamma, chains);
      MTable mt; mt.nseg = 1;
      MSeg& m = mt.s[0];
      m.F = F0; m.B = B0; m.Ut = Ut0; m.out = MARG + segMG[s];
      m.L = L; m.T = T; m.dirV = dirV; m.blockBase = 0;
      m.nrx = (dirV ? L : T) / 32;
      m.nfx = dirV ? T : L;
      int mb = 2 * m.nfx * m.nrx;
      k_marg_all<<<mb, 256, 0, stream>>>(mt, gamma);
    }
    k_combine<<<4096, 256, 0, stream>>>((const float*)d_in[0], (const float*)d_in[1],
                                        MARG, (float*)d_out);
  }
}

// Round 4
// 627.332 us; speedup vs baseline: 4.2829x; 1.2943x over previous
//
#include <hip/hip_runtime.h>
#include <stdint.h>

#define TC 4
#define CHUNK_BYTES 8192
#define CHUNK_F4 512

// ---------- helpers ----------
static __device__ __forceinline__ float lse16x2(const float* v, float igl2, float gln2, float uval)
{
  float a0=fmaxf(v[0],v[8]), a1=fmaxf(v[1],v[9]), a2=fmaxf(v[2],v[10]), a3=fmaxf(v[3],v[11]);
  float a4=fmaxf(v[4],v[12]),a5=fmaxf(v[5],v[13]),a6=fmaxf(v[6],v[14]),a7=fmaxf(v[7],v[15]);
  float b0=fmaxf(a0,a4), b1=fmaxf(a1,a5), b2=fmaxf(a2,a6), b3=fmaxf(a3,a7);
  float m = fmaxf(fmaxf(b0,b1), fmaxf(b2,b3));
  float e0 = exp2f((v[0]-m)*igl2) + exp2f((v[1]-m)*igl2);
  float e1 = exp2f((v[2]-m)*igl2) + exp2f((v[3]-m)*igl2);
  float e2 = exp2f((v[4]-m)*igl2) + exp2f((v[5]-m)*igl2);
  float e3 = exp2f((v[6]-m)*igl2) + exp2f((v[7]-m)*igl2);
  float e4 = exp2f((v[8]-m)*igl2) + exp2f((v[9]-m)*igl2);
  float e5 = exp2f((v[10]-m)*igl2) + exp2f((v[11]-m)*igl2);
  float e6 = exp2f((v[12]-m)*igl2) + exp2f((v[13]-m)*igl2);
  float e7 = exp2f((v[14]-m)*igl2) + exp2f((v[15]-m)*igl2);
  float s = ((e0+e1)+(e2+e3)) + ((e4+e5)+(e6+e7));
  float mo = __shfl_xor(m, 32);
  float m2 = fmaxf(m, mo);
  float sadj = s * exp2f((m - m2) * igl2);
  float stot = sadj + __shfl_xor(sadj, 32);
  return uval + m2 + gln2 * __log2f(stot);
}

static __device__ __forceinline__ float softmax32(float z)
{
  float zm = z;
  zm = fmaxf(zm, __shfl_xor(zm, 16));
  zm = fmaxf(zm, __shfl_xor(zm, 8));
  zm = fmaxf(zm, __shfl_xor(zm, 4));
  zm = fmaxf(zm, __shfl_xor(zm, 2));
  zm = fmaxf(zm, __shfl_xor(zm, 1));
  float p = exp2f((z - zm) * 1.4426950408889634f);
  float ps = p;
  ps += __shfl_xor(ps, 16);
  ps += __shfl_xor(ps, 8);
  ps += __shfl_xor(ps, 4);
  ps += __shfl_xor(ps, 2);
  ps += __shfl_xor(ps, 1);
  return p / ps;
}

// ---------- descriptor tables ----------
struct TSeg { const float* pw; uint16_t* PT; int L, Tt, Tpad, fStride, Xtot, dirV, blockBase, nx, ny; };
struct TTable { TSeg s[10]; int nseg; };
struct USeg { const float* U; float* Ut; int fs, nx, ny, L, T, dirV, blockBase; };
struct UTable { USeg s[10]; int nseg; };
struct DSeg { const uint16_t* PT; const float* Ut; float* F; float* B; int chainBase, T, Tt, Tpad; };
struct DTable { DSeg s[10]; int nseg; };
struct MSeg { const float* F; const float* B; const float* Ut; float* out; int L, T, dirV, blockBase, nrx, nfx; };
struct MTable { MSeg s[10]; int nseg; };

// ---------- transpose: pw(f32) -> PT(bf16, slice layout d = j*16 + (p2^((j>>1)&7))*2 + pr) ----------
// Each block: one aligned 32-x window, one j-half (16 j x 32 i = 512 planes), 32KB LDS.
__global__ __launch_bounds__(256) void k_transpose_all(TTable tbl)
{
  __shared__ uint16_t tile[512][32];    // row = i*16 + jl, col dword-swizzled
  int bid = blockIdx.x;
  int k = 0;
  for (int q = 1; q < tbl.nseg; q++) if (bid >= tbl.s[q].blockBase) k = q;
  TSeg sg = tbl.s[k];
  int r = bid - sg.blockBase;
  int jh = r & 1; r >>= 1;
  int w = r % sg.nx; int tmp = r / sg.nx;
  int fixed = tmp % sg.ny;
  int b = tmp / sg.ny;
  int g = fixed * sg.fStride;
  int a = g & 31;
  int xbase = w * 32 - a;            // global x at xs=0 (may be negative)
  if (xbase >= sg.Xtot) return;      // fully-invalid extra window
  int tid = threadIdx.x;
  int xx = tid & 31, ps = tid >> 5;
  int xg = xbase + xx;
  bool xok = (xg >= 0) && (xg < sg.Xtot);
  int j0 = jh * 16;
  size_t bbase = (size_t)b * 1024 * sg.L * sg.Tt;
  size_t abase = bbase + (size_t)(g - a) + (size_t)w * 32 + xx;   // 128B-aligned per lane-group
  size_t pstride = (size_t)sg.L * sg.Tt;
  // read 512 planes, 64 rows/thread, reg-staged 16-deep
  #pragma unroll
  for (int batch = 0; batch < 4; batch++) {
    float vv[16];
    #pragma unroll
    for (int q = 0; q < 16; q++) {
      int pl = batch * 128 + q * 8 + ps;              // row in [0,512)
      int gp = ((pl >> 4) << 5) + j0 + (pl & 15);     // global plane i*32+j
      vv[q] = 0.0f;
      if (xok) vv[q] = sg.pw[abase + (size_t)gp * pstride];
    }
    #pragma unroll
    for (int q = 0; q < 16; q++) {
      int pl = batch * 128 + q * 8 + ps;
      int i = pl >> 4, jl = pl & 15;
      uint32_t u = __float_as_uint(vv[q]);
      uint16_t bf = (uint16_t)((u + 0x7FFFu + ((u >> 16) & 1u)) >> 16);  // RNE to bf16
      int sw = (((j0 + jl) >> 1) & 3) ^ (((i >> 3) & 3) << 2);
      tile[pl][2 * (((xx >> 1) ^ sw) & 15) + (xx & 1)] = bf;
    }
  }
  __syncthreads();
  uint32_t* PTd = (uint32_t*)sg.PT;
  #pragma unroll
  for (int w8 = 0; w8 < 8; w8++) {
    int gidx = w8 * 256 + tid;       // 32 xs * 64 quads per j-half
    int xs = gidx >> 6;
    int qd = gidx & 63;
    int jl = qd >> 2, j = j0 + jl;
    int perm3 = (j >> 1) & 7;
    int xv = xbase + xs;
    if (xv < 0 || xv >= sg.Xtot) continue;
    uint32_t pk[4];
    #pragma unroll
    for (int e = 0; e < 4; e++) {
      int ww = (qd & 3) * 4 + e;          // dword-in-j-group 0..15
      int pos = ww >> 1, pr = ww & 1;
      int i0 = ((pos ^ perm3) << 2) + pr * 2;
      int sw0 = ((j >> 1) & 3) ^ (((i0 >> 3) & 3) << 2);
      int col = 2 * (((xs >> 1) ^ sw0) & 15) + (xs & 1);
      uint32_t v0 = tile[i0 * 16 + jl][col];
      uint32_t v1 = tile[(i0 + 1) * 16 + jl][col];
      pk[e] = v0 | (v1 << 16);
    }
    int chain, tsl;
    if (sg.dirV) { chain = b * sg.Xtot + xv; tsl = fixed; }
    else         { chain = b * sg.ny + fixed; tsl = xv; }
    *(uint4*)&PTd[((size_t)chain * sg.Tpad + tsl) * 512 + (size_t)j * 16 + (qd & 3) * 4] =
        make_uint4(pk[0], pk[1], pk[2], pk[3]);
  }
}

// ---------- unary transpose: U[b,c,(plane)] -> Ut[chain][t][c] ----------
__global__ __launch_bounds__(256) void k_ut_all(UTable tbl)
{
  __shared__ float tile[32][33];
  int bid = blockIdx.x;
  int k = 0;
  for (int q = 1; q < tbl.nseg; q++) if (bid >= tbl.s[q].blockBase) k = q;
  USeg sg = tbl.s[k];
  int r = bid - sg.blockBase;
  int bx = r % sg.nx; int tmp = r / sg.nx;
  int fixed = tmp % sg.ny;
  int b = tmp / sg.ny;
  int tid = threadIdx.x;
  size_t LT = (size_t)sg.L * sg.T;
  int x0 = bx * 32;
  int xx = tid & 31;
  #pragma unroll
  for (int it = 0; it < 4; it++) {
    int c = (tid >> 5) + it * 8;
    tile[xx][c] = sg.U[(size_t)b * 32 * LT + (size_t)c * LT + (size_t)fixed * sg.fs + x0 + xx];
  }
  __syncthreads();
  int cw = tid & 31;
  #pragma unroll
  for (int it = 0; it < 4; it++) {
    int xw = (tid >> 5) + it * 8;
    int chain = sg.dirV ? b * sg.L + x0 + xw : b * sg.L + fixed;
    int tIdx  = sg.dirV ? fixed : x0 + xw;
    sg.Ut[((size_t)chain * sg.T + tIdx) * 32 + cw] = tile[xw][cw];
  }
}

// ---------- DP: fwd and bwd chains concurrently; one wave per chain ----------
__global__ __launch_bounds__(64) void k_dp_all(DTable tbl, const float* __restrict__ gamma, int nDP)
{
  __shared__ __align__(16) unsigned char lds[2 * CHUNK_BYTES];
  int bid = blockIdx.x;
  int isB = (bid >= nDP) ? 1 : 0;
  bid -= isB * nDP;
  int k = 0;
  for (int q = 1; q < tbl.nseg; q++) if (bid >= tbl.s[q].chainBase) k = q;
  DSeg sg = tbl.s[k];
  int chain = bid - sg.chainBase;
  int T = sg.T, Tt = sg.Tt;
  int tid = threadIdx.x, j = tid & 31, h = tid >> 5;
  float g = fmaxf(gamma[0], 0.01f);
  float igl2 = (1.0f / g) * 1.4426950408889634f;
  float gln2 = g * 0.6931471805599453f;
  const float* Utc = sg.Ut + (size_t)chain * T * 32;
  float* Oc = (isB ? sg.B : sg.F) + (size_t)chain * T * 32;
  const float4* src = (const float4*)(sg.PT + (size_t)chain * sg.Tpad * 1024);
  int nch = sg.Tpad / TC;
  int perm3 = (j >> 1) & 7;
  int gbase = h * 48;
  float4 stg[8];
  if (!isB) {
    float cur = Utc[j];
    if (h == 0) Oc[j] = cur;
    #pragma unroll
    for (int q = 0; q < 8; q++) stg[q] = src[q * 64 + tid];
    int buf = 0;
    for (int ch = 0; ch < nch; ch++) {
      float4* dst = (float4*)(lds + buf * CHUNK_BYTES);
      #pragma unroll
      for (int q = 0; q < 8; q++) dst[q * 64 + tid] = stg[q];
      if (ch + 1 < nch) {
        const float4* s2 = src + (size_t)(ch + 1) * CHUNK_F4;
        #pragma unroll
        for (int q = 0; q < 8; q++) stg[q] = s2[q * 64 + tid];
      }
      #pragma unroll
      for (int ss = 0; ss < TC; ss++) {
        int s = ch * TC + ss;
        if (s >= Tt) break;
        const uint32_t* sl = (const uint32_t*)(lds + buf * CHUNK_BYTES + ss * 2048);
        float v[16];
        #pragma unroll
        for (int rr = 0; rr < 4; rr++) {
          int pos = (4 * h + rr) ^ perm3;
          uint2 dv = *(const uint2*)&sl[j * 16 + pos * 2];
          v[rr * 4 + 0] = __uint_as_float(dv.x << 16);
          v[rr * 4 + 1] = __uint_as_float(dv.x & 0xFFFF0000u);
          v[rr * 4 + 2] = __uint_as_float(dv.y << 16);
          v[rr * 4 + 3] = __uint_as_float(dv.y & 0xFFFF0000u);
        }
        #pragma unroll
        for (int q = 0; q < 16; q++) v[q] += __shfl(cur, gbase + q);
        float uval = Utc[(size_t)(s + 1) * 32 + j];
        cur = lse16x2(v, igl2, gln2, uval);
        if (h == 0) Oc[(size_t)(s + 1) * 32 + j] = cur;
      }
      buf ^= 1;
    }
  } else {
    int p2i = j >> 2, pri = (j >> 1) & 1, loi = j & 1;
    float cur = Utc[(size_t)(T - 1) * 32 + j];
    if (h == 0) Oc[(size_t)(T - 1) * 32 + j] = cur;
    {
      const float4* s2 = src + (size_t)(nch - 1) * CHUNK_F4;
      #pragma unroll
      for (int q = 0; q < 8; q++) stg[q] = s2[q * 64 + tid];
    }
    int buf = 0;
    for (int ch = nch - 1; ch >= 0; ch--) {
      float4* dst = (float4*)(lds + buf * CHUNK_BYTES);
      #pragma unroll
      for (int q = 0; q < 8; q++) dst[q * 64 + tid] = stg[q];
      if (ch > 0) {
        const float4* s2 = src + (size_t)(ch - 1) * CHUNK_F4;
        #pragma unroll
        for (int q = 0; q < 8; q++) stg[q] = s2[q * 64 + tid];
      }
      #pragma unroll
      for (int ss = TC - 1; ss >= 0; ss--) {
        int s = ch * TC + ss;
        if (s >= Tt) continue;
        const uint16_t* row16 = (const uint16_t*)(lds + buf * CHUNK_BYTES + ss * 2048);
        float v[16];
        #pragma unroll
        for (int jj = 0; jj < 16; jj++) {
          int u16idx = (16 * h + jj) * 32 + ((p2i ^ (jj >> 1)) * 2 + pri) * 2 + loi;
          v[jj] = __uint_as_float((uint32_t)row16[u16idx] << 16);
        }
        #pragma unroll
        for (int q = 0; q < 16; q++) v[q] += __shfl(cur, gbase + q);
        float uval = Utc[(size_t)s * 32 + j];
        cur = lse16x2(v, igl2, gln2, uval);
        if (h == 0) Oc[(size_t)s * 32 + j] = cur;
      }
      buf ^= 1;
    }
  }
}

// ---------- marginals: softmax((F+B-Ut)/g) over c, LDS-transposed coalesced write ----------
__global__ __launch_bounds__(256) void k_marg_all(MTable tbl, const float* __restrict__ gamma)
{
  __shared__ float sm[32][33];
  int bid = blockIdx.x;
  int k = 0;
  for (int q = 1; q < tbl.nseg; q++) if (bid >= tbl.s[q].blockBase) k = q;
  MSeg sg = tbl.s[k];
  int r = bid - sg.blockBase;
  int rx = r % sg.nrx; int tmp = r / sg.nrx;
  int fx = tmp % sg.nfx; int b = tmp / sg.nfx;
  int tid = threadIdx.x;
  float g = fmaxf(gamma[0], 0.01f);
  float ig = 1.0f / g;
  int c = tid & 31;
  int L = sg.L, T = sg.T;
  size_t LT = (size_t)L * T;
  int RA = sg.dirV ? L : T;
  int r0 = rx * 32;
  #pragma unroll
  for (int pass = 0; pass < 4; pass++) {
    int rr = (tid >> 5) + pass * 8;
    int rowAxis = r0 + rr;
    int chain = sg.dirV ? b * L + rowAxis : b * L + fx;
    int t = sg.dirV ? fx : rowAxis;
    size_t idx = ((size_t)chain * T + t) * 32 + c;
    float z = (sg.F[idx] + sg.B[idx] - sg.Ut[idx]) * ig;
    sm[rr][c] = softmax32(z);
  }
  __syncthreads();
  size_t obase = (size_t)b * 32 * LT + (size_t)fx * RA + r0;
  #pragma unroll
  for (int pass = 0; pass < 4; pass++) {
    int cc = (tid >> 5) + pass * 8;
    sg.out[obase + (size_t)cc * LT + (tid & 31)] = sm[tid & 31][cc];
  }
}

// ---------- combine ----------
__global__ __launch_bounds__(256) void k_combine(
    const float* __restrict__ uh0, const float* __restrict__ uv0,
    const float* __restrict__ MB, float* __restrict__ out)
{
  int idx = blockIdx.x * 256 + threadIdx.x;
  int x = idx & 127, y = (idx >> 7) & 127;
  int bc = idx >> 14;
  float mh0 = MB[idx];
  float mv0 = MB[1048576 + idx];
  int cnt = 1 + ((y & 1) << 1) + (x & 1);
  int coff = bc * 4096 + ((y >> 1) << 6) + (x >> 1);
  const float* cb = MB + 2097152 + (size_t)(cnt - 1) * 524288;
  float mhc = cb[coff];
  float mvc = cb[262144 + coff];
  float mha = mh0 + mhc, mva = mv0 + mvc;
  float avg = (mha + mva) * 0.25f;
  const float A = 0.0078125f;
  out[idx]           = uh0[idx] - A * (mh0 - avg);
  out[1048576 + idx] = uv0[idx] - A * (mv0 - avg);
  out[2097152 + idx] = mha;
  out[3145728 + idx] = mva;
}

// ---------- launch ----------
static void fill_tseg(TSeg& t, const float* pw, uint16_t* PT, int L, int T, int dirV, int blockBase)
{
  int Tt = T - 1;
  t.pw = pw; t.PT = PT;
  t.L = L; t.Tt = Tt; t.Tpad = T;
  t.fStride = dirV ? L : Tt;
  t.Xtot = dirV ? L : Tt;
  t.dirV = dirV;
  int pad = (t.fStride & 31) ? 31 : 0;     // extra window for misaligned rows
  t.nx = (t.Xtot + pad + 31) / 32;
  t.ny = dirV ? Tt : L;
  t.blockBase = blockBase;
}

extern "C" void kernel_launch(void* const* d_in, const int* in_sizes, int n_in,
                              void* d_out, int out_size, void* d_ws, size_t ws_size,
                              hipStream_t stream)
{
  (void)in_sizes; (void)n_in; (void)out_size;
  const float* gamma = (const float*)d_in[20];
  unsigned char* ws = (unsigned char*)d_ws;

  int segL[10], segT[10];
  const float* segPW[10]; const float* segUU[10];
  size_t segMG[10];
  for (int lvl = 0; lvl < 5; lvl++) {
    int H = lvl ? 64 : 128, W = H;
    int si = lvl * 2;
    segL[si] = H; segT[si] = W;
    segPW[si] = (const float*)d_in[lvl * 4 + 2];
    segUU[si] = (const float*)d_in[lvl * 4 + 0];
    segL[si + 1] = W; segT[si + 1] = H;
    segPW[si + 1] = (const float*)d_in[lvl * 4 + 3];
    segUU[si + 1] = (const float*)d_in[lvl * 4 + 1];
    if (lvl == 0) { segMG[0] = 0; segMG[1] = 1048576; }
    else { segMG[si] = 2097152 + (size_t)(lvl - 1) * 524288; segMG[si + 1] = segMG[si] + 262144; }
  }

  const size_t NEED = 318767104ull;  // PT 256MiB (MARG aliased) + F/B/Ut 16MiB each
  if (ws_size >= NEED) {
    uint16_t* PT0 = (uint16_t*)ws;
    float* MARG = (float*)ws;                       // aliased over PT, used after DP
    float* F0  = (float*)(ws + 268435456ull);
    float* B0  = (float*)(ws + 285212672ull);
    float* Ut0 = (float*)(ws + 301989888ull);

    TTable tt; UTable ut; DTable dt; MTable mt;
    tt.nseg = 10; ut.nseg = 10; dt.nseg = 10; mt.nseg = 10;
    size_t ptOff = 0, fuOff = 0;
    int tB = 0, uB = 0, cB = 0, mB = 0;
    for (int s = 0; s < 10; s++) {
      int dirV = s & 1;
      int L = segL[s], T = segT[s];
      int chains = 2 * L;
      fill_tseg(tt.s[s], segPW[s], PT0 + ptOff, L, T, dirV, tB);
      tB += tt.s[s].nx * tt.s[s].ny * 2 * 2;   // x-windows * rows * B * j-halves
      USeg& u = ut.s[s];
      u.U = segUU[s]; u.Ut = Ut0 + fuOff;
      u.fs = dirV ? L : T;
      u.nx = (dirV ? L : T) / 32;
      u.ny = dirV ? T : L;
      u.L = L; u.T = T; u.dirV = dirV;
      u.blockBase = uB;
      uB += u.nx * u.ny * 2;
      DSeg& d = dt.s[s];
      d.PT = PT0 + ptOff; d.Ut = Ut0 + fuOff;
      d.F = F0 + fuOff; d.B = B0 + fuOff;
      d.chainBase = cB; d.T = T; d.Tt = T - 1; d.Tpad = T;
      cB += chains;
      MSeg& m = mt.s[s];
      m.F = F0 + fuOff; m.B = B0 + fuOff; m.Ut = Ut0 + fuOff;
      m.out = MARG + segMG[s];
      m.L = L; m.T = T; m.dirV = dirV;
      m.blockBase = mB;
      m.nrx = (dirV ? L : T) / 32;
      m.nfx = dirV ? T : L;
      mB += 2 * m.nfx * m.nrx;
      ptOff += (size_t)chains * T * 1024;
      fuOff += (size_t)chains * T * 32;
    }
    k_transpose_all<<<tB, 256, 0, stream>>>(tt);
    k_ut_all<<<uB, 256, 0, stream>>>(ut);
    k_dp_all<<<2 * cB, 64, 0, stream>>>(dt, gamma, cB);
    k_marg_all<<<mB, 256, 0, stream>>>(mt, gamma);
    k_combine<<<4096, 256, 0, stream>>>((const float*)d_in[0], (const float*)d_in[1],
                                        MARG, (float*)d_out);
  } else {
    // level-serial fallback: PT@0 (64MiB), F@64Mi, B@68Mi, Ut@72Mi... MARG separate
    uint16_t* PT0 = (uint16_t*)ws;
    float* F0  = (float*)(ws + 67108864ull);
    float* B0  = (float*)(ws + 71303168ull);
    float* Ut0 = (float*)(ws + 75497472ull);
    float* MARG = (float*)(ws + 79691776ull);
    for (int s = 0; s < 10; s++) {
      int dirV = s & 1;
      int L = segL[s], T = segT[s];
      int chains = 2 * L;
      TTable tt; tt.nseg = 1;
      fill_tseg(tt.s[0], segPW[s], PT0, L, T, dirV, 0);
      int nb = tt.s[0].nx * tt.s[0].ny * 2 * 2;
      k_transpose_all<<<nb, 256, 0, stream>>>(tt);
      UTable ut; ut.nseg = 1;
      USeg& u = ut.s[0];
      u.U = segUU[s]; u.Ut = Ut0;
      u.fs = dirV ? L : T;
      u.nx = (dirV ? L : T) / 32;
      u.ny = dirV ? T : L;
      u.L = L; u.T = T; u.dirV = dirV; u.blockBase = 0;
      int ub = u.nx * u.ny * 2;
      k_ut_all<<<ub, 256, 0, stream>>>(ut);
      DTable dt; dt.nseg = 1;
      DSeg& d = dt.s[0];
      d.PT = PT0; d.Ut = Ut0; d.F = F0; d.B = B0;
      d.chainBase = 0; d.T = T; d.Tt = T - 1; d.Tpad = T;
      k_dp_all<<<2 * chains, 64, 0, stream>>>(dt, gamma, chains);
      MTable mt; mt.nseg = 1;
      MSeg& m = mt.s[0];
      m.F = F0; m.B = B0; m.Ut = Ut0; m.out = MARG + segMG[s];
      m.L = L; m.T = T; m.dirV = dirV; m.blockBase = 0;
      m.nrx = (dirV ? L : T) / 32;
      m.nfx = dirV ? T : L;
      int mb = 2 * m.nfx * m.nrx;
      k_marg_all<<<mb, 256, 0, stream>>>(mt, gamma);
    }
    k_combine<<<4096, 256, 0, stream>>>((const float*)d_in[0], (const float*)d_in[1],
                                        MARG, (float*)d_out);
  }
}

// Round 5
// 435.454 us; speedup vs baseline: 6.1701x; 1.4406x over previous
//
#include <hip/hip_runtime.h>
#include <stdint.h>

#define TC 4
#define CHUNK_BYTES 8192
#define CHUNK_F4 512

// ---------- helpers ----------
static __device__ __forceinline__ float lse16x2(const float* v, float igl2, float gln2, float uval)
{
  float a0=fmaxf(v[0],v[8]), a1=fmaxf(v[1],v[9]), a2=fmaxf(v[2],v[10]), a3=fmaxf(v[3],v[11]);
  float a4=fmaxf(v[4],v[12]),a5=fmaxf(v[5],v[13]),a6=fmaxf(v[6],v[14]),a7=fmaxf(v[7],v[15]);
  float b0=fmaxf(a0,a4), b1=fmaxf(a1,a5), b2=fmaxf(a2,a6), b3=fmaxf(a3,a7);
  float m = fmaxf(fmaxf(b0,b1), fmaxf(b2,b3));
  float e0 = exp2f((v[0]-m)*igl2) + exp2f((v[1]-m)*igl2);
  float e1 = exp2f((v[2]-m)*igl2) + exp2f((v[3]-m)*igl2);
  float e2 = exp2f((v[4]-m)*igl2) + exp2f((v[5]-m)*igl2);
  float e3 = exp2f((v[6]-m)*igl2) + exp2f((v[7]-m)*igl2);
  float e4 = exp2f((v[8]-m)*igl2) + exp2f((v[9]-m)*igl2);
  float e5 = exp2f((v[10]-m)*igl2) + exp2f((v[11]-m)*igl2);
  float e6 = exp2f((v[12]-m)*igl2) + exp2f((v[13]-m)*igl2);
  float e7 = exp2f((v[14]-m)*igl2) + exp2f((v[15]-m)*igl2);
  float s = ((e0+e1)+(e2+e3)) + ((e4+e5)+(e6+e7));
  float mo = __shfl_xor(m, 32);
  float m2 = fmaxf(m, mo);
  float sadj = s * exp2f((m - m2) * igl2);
  float stot = sadj + __shfl_xor(sadj, 32);
  return uval + m2 + gln2 * __log2f(stot);
}

static __device__ __forceinline__ float softmax32(float z)
{
  float zm = z;
  zm = fmaxf(zm, __shfl_xor(zm, 16));
  zm = fmaxf(zm, __shfl_xor(zm, 8));
  zm = fmaxf(zm, __shfl_xor(zm, 4));
  zm = fmaxf(zm, __shfl_xor(zm, 2));
  zm = fmaxf(zm, __shfl_xor(zm, 1));
  float p = exp2f((z - zm) * 1.4426950408889634f);
  float ps = p;
  ps += __shfl_xor(ps, 16);
  ps += __shfl_xor(ps, 8);
  ps += __shfl_xor(ps, 4);
  ps += __shfl_xor(ps, 2);
  ps += __shfl_xor(ps, 1);
  return p / ps;
}

static __device__ __forceinline__ uint32_t pkbf(float a, float b)
{
  uint32_t ua = __float_as_uint(a), ub = __float_as_uint(b);
  ua = (ua + 0x7FFFu + ((ua >> 16) & 1u)) >> 16;
  ub = (ub + 0x7FFFu + ((ub >> 16) & 1u)) & 0xFFFF0000u;
  return ua | ub;
}

// ---------- descriptor tables ----------
struct TSeg { const float* pw; uint16_t* PT; int L, Tt, Tpad, fStride, Xtot, dirV, blockBase, nx, ny; };
struct TTable { TSeg s[10]; int nseg; };
struct USeg { const float* U; float* Ut; int fs, nx, ny, L, T, dirV, blockBase; };
struct UTable { USeg s[10]; int nseg; };
struct DSeg { const uint16_t* PT; const float* Ut; float* F; float* B; int chainBase, T, Tt, Tpad; };
struct DTable { DSeg s[10]; int nseg; };
struct MSeg { const float* F; const float* B; const float* Ut; float* out; int L, T, dirV, blockBase, nrx, nfx; };
struct MTable { MSeg s[10]; int nseg; };

// ---------- transpose: pw(f32) -> PT(bf16). Block = (b, fixed, 4-j group, 128-x window).
// LDS tile[plane=i*4+jl][x] bf16, dword-swizzled: dword col c = (x>>1) ^ sw, sw=((j>>1)&3)^(((i>>3)&3)<<2).
__global__ __launch_bounds__(256) void k_transpose_all(TTable tbl)
{
  __shared__ uint16_t tile[128][128];    // 32 KB
  int bid = blockIdx.x;
  int k = 0;
  for (int q = 1; q < tbl.nseg; q++) if (bid >= tbl.s[q].blockBase) k = q;
  TSeg sg = tbl.s[k];
  int r = bid - sg.blockBase;
  int jg = r & 7; r >>= 3;
  int w = r % sg.nx; int tmp = r / sg.nx;
  int fixed = tmp % sg.ny;
  int b = tmp / sg.ny;
  int j0 = jg * 4;
  int g = fixed * sg.fStride;
  int a = g & 31;
  int xbase = w * 128 - a;
  if (xbase >= sg.Xtot) return;
  int tid = threadIdx.x;
  int kx = tid & 31, psub = tid >> 5;
  int pstride = sg.L * sg.Tt;
  int clampMax = 2048 * pstride - 4;
  int jthr = j0 + (psub & 3);
  int swj = (jthr >> 1) & 3;
  int gp0 = ((psub >> 2) << 5) + jthr;
  int idx0 = ((b << 10) + gp0) * pstride + (g - a) + (w << 7) + (kx << 2);
  const float* pw = sg.pw;
  #pragma unroll
  for (int hp = 0; hp < 2; hp++) {
    float4 st[8];
    #pragma unroll
    for (int q = 0; q < 8; q++) {
      int batch = hp * 8 + q;
      int idx = idx0 + batch * (pstride << 6);
      idx = idx > clampMax ? clampMax : idx;
      st[q] = *(const float4*)(pw + idx);
    }
    #pragma unroll
    for (int q = 0; q < 8; q++) {
      int batch = hp * 8 + q;
      int i = 2 * batch + (psub >> 2);
      int sw = swj ^ (((i >> 3) & 3) << 2);
      int pl = batch * 8 + psub;
      uint32_t pk0 = pkbf(st[q].x, st[q].y);
      uint32_t pk1 = pkbf(st[q].z, st[q].w);
      if (sw & 1) { uint32_t tswp = pk0; pk0 = pk1; pk1 = tswp; }
      *(uint2*)((unsigned char*)tile + pl * 256 + 8 * (kx ^ (sw >> 1))) = make_uint2(pk0, pk1);
    }
  }
  __syncthreads();
  uint32_t* PTd = (uint32_t*)sg.PT;
  #pragma unroll
  for (int w8 = 0; w8 < 8; w8++) {
    int gidx = w8 * 256 + tid;
    int xs = gidx >> 4;            // 0..127
    int q = gidx & 15;             // quad within 64-dword segment
    int xv = xbase + xs;
    if (xv < 0 || xv >= sg.Xtot) continue;
    int jl = q >> 2, j = j0 + jl;
    int perm3 = (j >> 1) & 7;
    int swjW = (j >> 1) & 3;
    uint32_t pk[4];
    #pragma unroll
    for (int e = 0; e < 4; e++) {
      int wd = ((q & 3) << 2) + e;       // 0..15 within j
      int pos = wd >> 1, pr = wd & 1;
      int i0 = ((pos ^ perm3) << 2) + pr * 2;
      int sw = swjW ^ (((i0 >> 3) & 3) << 2);
      int c = (xs >> 1) ^ sw;
      int u16c = (c << 1) | (xs & 1);
      int r0 = (i0 << 2) + jl;
      uint32_t v0 = tile[r0][u16c];
      uint32_t v1 = tile[r0 + 4][u16c];
      pk[e] = v0 | (v1 << 16);
    }
    int chain, tsl;
    if (sg.dirV) { chain = b * sg.Xtot + xv; tsl = fixed; }
    else         { chain = b * sg.ny + fixed; tsl = xv; }
    *(uint4*)&PTd[((size_t)chain * sg.Tpad + tsl) * 512 + j * 16 + (q & 3) * 4] =
        make_uint4(pk[0], pk[1], pk[2], pk[3]);
  }
}

// ---------- unary transpose: U[b,c,(plane)] -> Ut[chain][t][c] ----------
__global__ __launch_bounds__(256) void k_ut_all(UTable tbl)
{
  __shared__ float tile[32][33];
  int bid = blockIdx.x;
  int k = 0;
  for (int q = 1; q < tbl.nseg; q++) if (bid >= tbl.s[q].blockBase) k = q;
  USeg sg = tbl.s[k];
  int r = bid - sg.blockBase;
  int bx = r % sg.nx; int tmp = r / sg.nx;
  int fixed = tmp % sg.ny;
  int b = tmp / sg.ny;
  int tid = threadIdx.x;
  size_t LT = (size_t)sg.L * sg.T;
  int x0 = bx * 32;
  int xx = tid & 31;
  #pragma unroll
  for (int it = 0; it < 4; it++) {
    int c = (tid >> 5) + it * 8;
    tile[xx][c] = sg.U[(size_t)b * 32 * LT + (size_t)c * LT + (size_t)fixed * sg.fs + x0 + xx];
  }
  __syncthreads();
  int cw = tid & 31;
  #pragma unroll
  for (int it = 0; it < 4; it++) {
    int xw = (tid >> 5) + it * 8;
    int chain = sg.dirV ? b * sg.L + x0 + xw : b * sg.L + fixed;
    int tIdx  = sg.dirV ? fixed : x0 + xw;
    sg.Ut[((size_t)chain * sg.T + tIdx) * 32 + cw] = tile[xw][cw];
  }
}

// ---------- DP: fwd and bwd chains concurrently; one wave per chain ----------
__global__ __launch_bounds__(64) void k_dp_all(DTable tbl, const float* __restrict__ gamma, int nDP)
{
  __shared__ __align__(16) unsigned char lds[2 * CHUNK_BYTES];
  int bid = blockIdx.x;
  int isB = (bid >= nDP) ? 1 : 0;
  bid -= isB * nDP;
  int k = 0;
  for (int q = 1; q < tbl.nseg; q++) if (bid >= tbl.s[q].chainBase) k = q;
  DSeg sg = tbl.s[k];
  int chain = bid - sg.chainBase;
  int T = sg.T, Tt = sg.Tt;
  int tid = threadIdx.x, j = tid & 31, h = tid >> 5;
  float g = fmaxf(gamma[0], 0.01f);
  float igl2 = (1.0f / g) * 1.4426950408889634f;
  float gln2 = g * 0.6931471805599453f;
  const float* Utc = sg.Ut + (size_t)chain * T * 32;
  float* Oc = (isB ? sg.B : sg.F) + (size_t)chain * T * 32;
  const float4* src = (const float4*)(sg.PT + (size_t)chain * sg.Tpad * 1024);
  int nch = sg.Tpad / TC;
  int perm3 = (j >> 1) & 7;
  int gbase = h * 48;
  float4 stg[8];
  if (!isB) {
    float cur = Utc[j];
    if (h == 0) Oc[j] = cur;
    #pragma unroll
    for (int q = 0; q < 8; q++) stg[q] = src[q * 64 + tid];
    int buf = 0;
    for (int ch = 0; ch < nch; ch++) {
      float4* dst = (float4*)(lds + buf * CHUNK_BYTES);
      #pragma unroll
      for (int q = 0; q < 8; q++) dst[q * 64 + tid] = stg[q];
      if (ch + 1 < nch) {
        const float4* s2 = src + (size_t)(ch + 1) * CHUNK_F4;
        #pragma unroll
        for (int q = 0; q < 8; q++) stg[q] = s2[q * 64 + tid];
      }
      #pragma unroll
      for (int ss = 0; ss < TC; ss++) {
        int s = ch * TC + ss;
        if (s >= Tt) break;
        const uint32_t* sl = (const uint32_t*)(lds + buf * CHUNK_BYTES + ss * 2048);
        float v[16];
        #pragma unroll
        for (int rr = 0; rr < 4; rr++) {
          int pos = (4 * h + rr) ^ perm3;
          uint2 dv = *(const uint2*)&sl[j * 16 + pos * 2];
          v[rr * 4 + 0] = __uint_as_float(dv.x << 16);
          v[rr * 4 + 1] = __uint_as_float(dv.x & 0xFFFF0000u);
          v[rr * 4 + 2] = __uint_as_float(dv.y << 16);
          v[rr * 4 + 3] = __uint_as_float(dv.y & 0xFFFF0000u);
        }
        #pragma unroll
        for (int q = 0; q < 16; q++) v[q] += __shfl(cur, gbase + q);
        float uval = Utc[(size_t)(s + 1) * 32 + j];
        cur = lse16x2(v, igl2, gln2, uval);
        if (h == 0) Oc[(size_t)(s + 1) * 32 + j] = cur;
      }
      buf ^= 1;
    }
  } else {
    int p2i = j >> 2, pri = (j >> 1) & 1, loi = j & 1;
    float cur = Utc[(size_t)(T - 1) * 32 + j];
    if (h == 0) Oc[(size_t)(T - 1) * 32 + j] = cur;
    {
      const float4* s2 = src + (size_t)(nch - 1) * CHUNK_F4;
      #pragma unroll
      for (int q = 0; q < 8; q++) stg[q] = s2[q * 64 + tid];
    }
    int buf = 0;
    for (int ch = nch - 1; ch >= 0; ch--) {
      float4* dst = (float4*)(lds + buf * CHUNK_BYTES);
      #pragma unroll
      for (int q = 0; q < 8; q++) dst[q * 64 + tid] = stg[q];
      if (ch > 0) {
        const float4* s2 = src + (size_t)(ch - 1) * CHUNK_F4;
        #pragma unroll
        for (int q = 0; q < 8; q++) stg[q] = s2[q * 64 + tid];
      }
      #pragma unroll
      for (int ss = TC - 1; ss >= 0; ss--) {
        int s = ch * TC + ss;
        if (s >= Tt) continue;
        const uint16_t* row16 = (const uint16_t*)(lds + buf * CHUNK_BYTES + ss * 2048);
        float v[16];
        #pragma unroll
        for (int jj = 0; jj < 16; jj++) {
          int u16idx = (16 * h + jj) * 32 + ((p2i ^ (jj >> 1)) * 2 + pri) * 2 + loi;
          v[jj] = __uint_as_float((uint32_t)row16[u16idx] << 16);
        }
        #pragma unroll
        for (int q = 0; q < 16; q++) v[q] += __shfl(cur, gbase + q);
        float uval = Utc[(size_t)s * 32 + j];
        cur = lse16x2(v, igl2, gln2, uval);
        if (h == 0) Oc[(size_t)s * 32 + j] = cur;
      }
      buf ^= 1;
    }
  }
}

// ---------- marginals: softmax((F+B-Ut)/g) over c, LDS-transposed coalesced write ----------
__global__ __launch_bounds__(256) void k_marg_all(MTable tbl, const float* __restrict__ gamma)
{
  __shared__ float sm[32][33];
  int bid = blockIdx.x;
  int k = 0;
  for (int q = 1; q < tbl.nseg; q++) if (bid >= tbl.s[q].blockBase) k = q;
  MSeg sg = tbl.s[k];
  int r = bid - sg.blockBase;
  int rx = r % sg.nrx; int tmp = r / sg.nrx;
  int fx = tmp % sg.nfx; int b = tmp / sg.nfx;
  int tid = threadIdx.x;
  float g = fmaxf(gamma[0], 0.01f);
  float ig = 1.0f / g;
  int c = tid & 31;
  int L = sg.L, T = sg.T;
  size_t LT = (size_t)L * T;
  int RA = sg.dirV ? L : T;
  int r0 = rx * 32;
  #pragma unroll
  for (int pass = 0; pass < 4; pass++) {
    int rr = (tid >> 5) + pass * 8;
    int rowAxis = r0 + rr;
    int chain = sg.dirV ? b * L + rowAxis : b * L + fx;
    int t = sg.dirV ? fx : rowAxis;
    size_t idx = ((size_t)chain * T + t) * 32 + c;
    float z = (sg.F[idx] + sg.B[idx] - sg.Ut[idx]) * ig;
    sm[rr][c] = softmax32(z);
  }
  __syncthreads();
  size_t obase = (size_t)b * 32 * LT + (size_t)fx * RA + r0;
  #pragma unroll
  for (int pass = 0; pass < 4; pass++) {
    int cc = (tid >> 5) + pass * 8;
    sg.out[obase + (size_t)cc * LT + (tid & 31)] = sm[tid & 31][cc];
  }
}

// ---------- combine ----------
__global__ __launch_bounds__(256) void k_combine(
    const float* __restrict__ uh0, const float* __restrict__ uv0,
    const float* __restrict__ MB, float* __restrict__ out)
{
  int idx = blockIdx.x * 256 + threadIdx.x;
  int x = idx & 127, y = (idx >> 7) & 127;
  int bc = idx >> 14;
  float mh0 = MB[idx];
  float mv0 = MB[1048576 + idx];
  int cnt = 1 + ((y & 1) << 1) + (x & 1);
  int coff = bc * 4096 + ((y >> 1) << 6) + (x >> 1);
  const float* cb = MB + 2097152 + (size_t)(cnt - 1) * 524288;
  float mhc = cb[coff];
  float mvc = cb[262144 + coff];
  float mha = mh0 + mhc, mva = mv0 + mvc;
  float avg = (mha + mva) * 0.25f;
  const float A = 0.0078125f;
  out[idx]           = uh0[idx] - A * (mh0 - avg);
  out[1048576 + idx] = uv0[idx] - A * (mv0 - avg);
  out[2097152 + idx] = mha;
  out[3145728 + idx] = mva;
}

// ---------- launch ----------
static void fill_tseg(TSeg& t, const float* pw, uint16_t* PT, int L, int T, int dirV, int blockBase)
{
  int Tt = T - 1;
  t.pw = pw; t.PT = PT;
  t.L = L; t.Tt = Tt; t.Tpad = T;
  t.fStride = dirV ? L : Tt;
  t.Xtot = dirV ? L : Tt;
  t.dirV = dirV;
  int pad = (t.fStride & 31) ? 31 : 0;     // alignment shift headroom
  t.nx = (t.Xtot + pad + 127) / 128;
  t.ny = dirV ? Tt : L;
  t.blockBase = blockBase;
}

extern "C" void kernel_launch(void* const* d_in, const int* in_sizes, int n_in,
                              void* d_out, int out_size, void* d_ws, size_t ws_size,
                              hipStream_t stream)
{
  (void)in_sizes; (void)n_in; (void)out_size;
  const float* gamma = (const float*)d_in[20];
  unsigned char* ws = (unsigned char*)d_ws;

  int segL[10], segT[10];
  const float* segPW[10]; const float* segUU[10];
  size_t segMG[10];
  for (int lvl = 0; lvl < 5; lvl++) {
    int H = lvl ? 64 : 128, W = H;
    int si = lvl * 2;
    segL[si] = H; segT[si] = W;
    segPW[si] = (const float*)d_in[lvl * 4 + 2];
    segUU[si] = (const float*)d_in[lvl * 4 + 0];
    segL[si + 1] = W; segT[si + 1] = H;
    segPW[si + 1] = (const float*)d_in[lvl * 4 + 3];
    segUU[si + 1] = (const float*)d_in[lvl * 4 + 1];
    if (lvl == 0) { segMG[0] = 0; segMG[1] = 1048576; }
    else { segMG[si] = 2097152 + (size_t)(lvl - 1) * 524288; segMG[si + 1] = segMG[si] + 262144; }
  }

  const size_t NEED = 318767104ull;  // PT 256MiB (MARG aliased) + F/B/Ut 16MiB each
  if (ws_size >= NEED) {
    uint16_t* PT0 = (uint16_t*)ws;
    float* MARG = (float*)ws;                       // aliased over PT, used after DP
    float* F0  = (float*)(ws + 268435456ull);
    float* B0  = (float*)(ws + 285212672ull);
    float* Ut0 = (float*)(ws + 301989888ull);

    TTable tt; UTable ut; DTable dt; MTable mt;
    tt.nseg = 10; ut.nseg = 10; dt.nseg = 10; mt.nseg = 10;
    size_t ptOff = 0, fuOff = 0;
    int tB = 0, uB = 0, cB = 0, mB = 0;
    for (int s = 0; s < 10; s++) {
      int dirV = s & 1;
      int L = segL[s], T = segT[s];
      int chains = 2 * L;
      fill_tseg(tt.s[s], segPW[s], PT0 + ptOff, L, T, dirV, tB);
      tB += 2 * tt.s[s].ny * tt.s[s].nx * 8;   // B * rows * x-windows * j-groups
      USeg& u = ut.s[s];
      u.U = segUU[s]; u.Ut = Ut0 + fuOff;
      u.fs = dirV ? L : T;
      u.nx = (dirV ? L : T) / 32;
      u.ny = dirV ? T : L;
      u.L = L; u.T = T; u.dirV = dirV;
      u.blockBase = uB;
      uB += u.nx * u.ny * 2;
      DSeg& d = dt.s[s];
      d.PT = PT0 + ptOff; d.Ut = Ut0 + fuOff;
      d.F = F0 + fuOff; d.B = B0 + fuOff;
      d.chainBase = cB; d.T = T; d.Tt = T - 1; d.Tpad = T;
      cB += chains;
      MSeg& m = mt.s[s];
      m.F = F0 + fuOff; m.B = B0 + fuOff; m.Ut = Ut0 + fuOff;
      m.out = MARG + segMG[s];
      m.L = L; m.T = T; m.dirV = dirV;
      m.blockBase = mB;
      m.nrx = (dirV ? L : T) / 32;
      m.nfx = dirV ? T : L;
      mB += 2 * m.nfx * m.nrx;
      ptOff += (size_t)chains * T * 1024;
      fuOff += (size_t)chains * T * 32;
    }
    k_transpose_all<<<tB, 256, 0, stream>>>(tt);
    k_ut_all<<<uB, 256, 0, stream>>>(ut);
    k_dp_all<<<2 * cB, 64, 0, stream>>>(dt, gamma, cB);
    k_marg_all<<<mB, 256, 0, stream>>>(mt, gamma);
    k_combine<<<4096, 256, 0, stream>>>((const float*)d_in[0], (const float*)d_in[1],
                                        MARG, (float*)d_out);
  } else {
    // level-serial fallback
    uint16_t* PT0 = (uint16_t*)ws;
    float* F0  = (float*)(ws + 67108864ull);
    float* B0  = (float*)(ws + 71303168ull);
    float* Ut0 = (float*)(ws + 75497472ull);
    float* MARG = (float*)(ws + 79691776ull);
    for (int s = 0; s < 10; s++) {
      int dirV = s & 1;
      int L = segL[s], T = segT[s];
      int chains = 2 * L;
      TTable tt; tt.nseg = 1;
      fill_tseg(tt.s[0], segPW[s], PT0, L, T, dirV, 0);
      int nb = 2 * tt.s[0].ny * tt.s[0].nx * 8;
      k_transpose_all<<<nb, 256, 0, stream>>>(tt);
      UTable ut; ut.nseg = 1;
      USeg& u = ut.s[0];
      u.U = segUU[s]; u.Ut = Ut0;
      u.fs = dirV ? L : T;
      u.nx = (dirV ? L : T) / 32;
      u.ny = dirV ? T : L;
      u.L = L; u.T = T; u.dirV = dirV; u.blockBase = 0;
      int ub = u.nx * u.ny * 2;
      k_ut_all<<<ub, 256, 0, stream>>>(ut);
      DTable dt; dt.nseg = 1;
      DSeg& d = dt.s[0];
      d.PT = PT0; d.Ut = Ut0; d.F = F0; d.B = B0;
      d.chainBase = 0; d.T = T; d.Tt = T - 1; d.Tpad = T;
      k_dp_all<<<2 * chains, 64, 0, stream>>>(dt, gamma, chains);
      MTable mt; mt.nseg = 1;
      MSeg& m = mt.s[0];
      m.F = F0; m.B = B0; m.Ut = Ut0; m.out = MARG + segMG[s];
      m.L = L; m.T = T; m.dirV = dirV; m.blockBase = 0;
      m.nrx = (dirV ? L : T) / 32;
      m.nfx = dirV ? T : L;
      int mb = 2 * m.nfx * m.nrx;
      k_marg_all<<<mb, 256, 0, stream>>>(mt, gamma);
    }
    k_combine<<<4096, 256, 0, stream>>>((const float*)d_in[0], (const float*)d_in[1],
                                        MARG, (float*)d_out);
  }
}

// Round 6
// 426.727 us; speedup vs baseline: 6.2963x; 1.0205x over previous
//
#include <hip/hip_runtime.h>
#include <stdint.h>

#define TC 2
#define CHUNK_BYTES 4096
#define CHUNK_F4 256

// ---------- helpers ----------
static __device__ __forceinline__ float lse16x2(const float* v, float igl2, float gln2, float uval)
{
  float a0=fmaxf(v[0],v[8]), a1=fmaxf(v[1],v[9]), a2=fmaxf(v[2],v[10]), a3=fmaxf(v[3],v[11]);
  float a4=fmaxf(v[4],v[12]),a5=fmaxf(v[5],v[13]),a6=fmaxf(v[6],v[14]),a7=fmaxf(v[7],v[15]);
  float b0=fmaxf(a0,a4), b1=fmaxf(a1,a5), b2=fmaxf(a2,a6), b3=fmaxf(a3,a7);
  float m = fmaxf(fmaxf(b0,b1), fmaxf(b2,b3));
  float e0 = exp2f((v[0]-m)*igl2) + exp2f((v[1]-m)*igl2);
  float e1 = exp2f((v[2]-m)*igl2) + exp2f((v[3]-m)*igl2);
  float e2 = exp2f((v[4]-m)*igl2) + exp2f((v[5]-m)*igl2);
  float e3 = exp2f((v[6]-m)*igl2) + exp2f((v[7]-m)*igl2);
  float e4 = exp2f((v[8]-m)*igl2) + exp2f((v[9]-m)*igl2);
  float e5 = exp2f((v[10]-m)*igl2) + exp2f((v[11]-m)*igl2);
  float e6 = exp2f((v[12]-m)*igl2) + exp2f((v[13]-m)*igl2);
  float e7 = exp2f((v[14]-m)*igl2) + exp2f((v[15]-m)*igl2);
  float s = ((e0+e1)+(e2+e3)) + ((e4+e5)+(e6+e7));
  float mo = __shfl_xor(m, 32);
  float m2 = fmaxf(m, mo);
  float sadj = s * exp2f((m - m2) * igl2);
  float stot = sadj + __shfl_xor(sadj, 32);
  return uval + m2 + gln2 * __log2f(stot);
}

static __device__ __forceinline__ float softmax32(float z)
{
  float zm = z;
  zm = fmaxf(zm, __shfl_xor(zm, 16));
  zm = fmaxf(zm, __shfl_xor(zm, 8));
  zm = fmaxf(zm, __shfl_xor(zm, 4));
  zm = fmaxf(zm, __shfl_xor(zm, 2));
  zm = fmaxf(zm, __shfl_xor(zm, 1));
  float p = exp2f((z - zm) * 1.4426950408889634f);
  float ps = p;
  ps += __shfl_xor(ps, 16);
  ps += __shfl_xor(ps, 8);
  ps += __shfl_xor(ps, 4);
  ps += __shfl_xor(ps, 2);
  ps += __shfl_xor(ps, 1);
  return p / ps;
}

static __device__ __forceinline__ uint32_t pkbf(float a, float b)
{
  uint32_t ua = __float_as_uint(a), ub = __float_as_uint(b);
  ua = (ua + 0x7FFFu + ((ua >> 16) & 1u)) >> 16;
  ub = (ub + 0x7FFFu + ((ub >> 16) & 1u)) & 0xFFFF0000u;
  return ua | ub;
}

// ---------- descriptor tables ----------
struct TSeg { const float* pw; uint16_t* PT; int L, Tt, Tpad, fStride, Xtot, dirV, blockBase, nx, ny; };
struct TTable { TSeg s[10]; int nseg; };
struct USeg { const float* U; float* Ut; int fs, nx, ny, L, T, dirV, blockBase; };
struct UTable { USeg s[10]; int nseg; };
struct DSeg { const uint16_t* PT; const float* Ut; float* F; float* B; int chainBase, T, Tt, Tpad; };
struct DTable { DSeg s[10]; int nseg; };
struct MSeg { const float* F; const float* B; const float* Ut; float* out; int L, T, dirV, blockBase, nrx, nfx; };
struct MTable { MSeg s[10]; int nseg; };

// ---------- transpose: pw(f32) -> PT(bf16). Block = (b, fixed, 4-j group, 128-x window). ----------
__global__ __launch_bounds__(256) void k_transpose_all(TTable tbl)
{
  __shared__ uint16_t tile[128][128];    // 32 KB
  int bid = blockIdx.x;
  int k = 0;
  for (int q = 1; q < tbl.nseg; q++) if (bid >= tbl.s[q].blockBase) k = q;
  TSeg sg = tbl.s[k];
  int r = bid - sg.blockBase;
  int jg = r & 7; r >>= 3;
  int w = r % sg.nx; int tmp = r / sg.nx;
  int fixed = tmp % sg.ny;
  int b = tmp / sg.ny;
  int j0 = jg * 4;
  int g = fixed * sg.fStride;
  int a = g & 31;
  int xbase = w * 128 - a;
  if (xbase >= sg.Xtot) return;
  int tid = threadIdx.x;
  int kx = tid & 31, psub = tid >> 5;
  int pstride = sg.L * sg.Tt;
  int clampMax = 2048 * pstride - 4;
  int jthr = j0 + (psub & 3);
  int swj = (jthr >> 1) & 3;
  int gp0 = ((psub >> 2) << 5) + jthr;
  int idx0 = ((b << 10) + gp0) * pstride + (g - a) + (w << 7) + (kx << 2);
  const float* pw = sg.pw;
  #pragma unroll
  for (int hp = 0; hp < 2; hp++) {
    float4 st[8];
    #pragma unroll
    for (int q = 0; q < 8; q++) {
      int batch = hp * 8 + q;
      int idx = idx0 + batch * (pstride << 6);
      idx = idx > clampMax ? clampMax : idx;
      st[q] = *(const float4*)(pw + idx);
    }
    #pragma unroll
    for (int q = 0; q < 8; q++) {
      int batch = hp * 8 + q;
      int i = 2 * batch + (psub >> 2);
      int sw = swj ^ (((i >> 3) & 3) << 2);
      int pl = batch * 8 + psub;
      uint32_t pk0 = pkbf(st[q].x, st[q].y);
      uint32_t pk1 = pkbf(st[q].z, st[q].w);
      if (sw & 1) { uint32_t tswp = pk0; pk0 = pk1; pk1 = tswp; }
      *(uint2*)((unsigned char*)tile + pl * 256 + 8 * (kx ^ (sw >> 1))) = make_uint2(pk0, pk1);
    }
  }
  __syncthreads();
  uint32_t* PTd = (uint32_t*)sg.PT;
  #pragma unroll
  for (int w8 = 0; w8 < 8; w8++) {
    int gidx = w8 * 256 + tid;
    int xs = gidx >> 4;            // 0..127
    int q = gidx & 15;
    int xv = xbase + xs;
    if (xv < 0 || xv >= sg.Xtot) continue;
    int jl = q >> 2, j = j0 + jl;
    int perm3 = (j >> 1) & 7;
    int swjW = (j >> 1) & 3;
    uint32_t pk[4];
    #pragma unroll
    for (int e = 0; e < 4; e++) {
      int wd = ((q & 3) << 2) + e;
      int pos = wd >> 1, pr = wd & 1;
      int i0 = ((pos ^ perm3) << 2) + pr * 2;
      int sw = swjW ^ (((i0 >> 3) & 3) << 2);
      int c = (xs >> 1) ^ sw;
      int u16c = (c << 1) | (xs & 1);
      int r0 = (i0 << 2) + jl;
      uint32_t v0 = tile[r0][u16c];
      uint32_t v1 = tile[r0 + 4][u16c];
      pk[e] = v0 | (v1 << 16);
    }
    int chain, tsl;
    if (sg.dirV) { chain = b * sg.Xtot + xv; tsl = fixed; }
    else         { chain = b * sg.ny + fixed; tsl = xv; }
    *(uint4*)&PTd[((size_t)chain * sg.Tpad + tsl) * 512 + j * 16 + (q & 3) * 4] =
        make_uint4(pk[0], pk[1], pk[2], pk[3]);
  }
}

// ---------- unary transpose: U[b,c,(plane)] -> Ut[chain][t][c], float4 writes ----------
__global__ __launch_bounds__(256) void k_ut_all(UTable tbl)
{
  __shared__ float tile[32][33];
  int bid = blockIdx.x;
  int k = 0;
  for (int q = 1; q < tbl.nseg; q++) if (bid >= tbl.s[q].blockBase) k = q;
  USeg sg = tbl.s[k];
  int r = bid - sg.blockBase;
  int bx = r % sg.nx; int tmp = r / sg.nx;
  int fixed = tmp % sg.ny;
  int b = tmp / sg.ny;
  int tid = threadIdx.x;
  size_t LT = (size_t)sg.L * sg.T;
  int x0 = bx * 32;
  int xx = tid & 31;
  #pragma unroll
  for (int it = 0; it < 4; it++) {
    int c = (tid >> 5) + it * 8;
    tile[xx][c] = sg.U[(size_t)b * 32 * LT + (size_t)c * LT + (size_t)fixed * sg.fs + x0 + xx];
  }
  __syncthreads();
  int xw = tid >> 3;
  int ci = (tid & 7) * 4;
  int chain = sg.dirV ? b * sg.L + x0 + xw : b * sg.L + fixed;
  int tIdx  = sg.dirV ? fixed : x0 + xw;
  float4 vv = make_float4(tile[xw][ci], tile[xw][ci + 1], tile[xw][ci + 2], tile[xw][ci + 3]);
  *(float4*)&sg.Ut[((size_t)chain * sg.T + tIdx) * 32 + ci] = vv;
}

// ---------- DP: fwd and bwd chains concurrently; one wave per chain; batched F/B flush ----------
__global__ __launch_bounds__(64) void k_dp_all(DTable tbl, const float* __restrict__ gamma, int nDP)
{
  __shared__ __align__(16) unsigned char lds[2 * CHUNK_BYTES + 1024];
  float* f_out = (float*)(lds + 2 * CHUNK_BYTES);
  int bid = blockIdx.x;
  int isB = (bid >= nDP) ? 1 : 0;
  bid -= isB * nDP;
  int k = 0;
  for (int q = 1; q < tbl.nseg; q++) if (bid >= tbl.s[q].chainBase) k = q;
  DSeg sg = tbl.s[k];
  int chain = bid - sg.chainBase;
  int T = sg.T, Tt = sg.Tt;
  int tid = threadIdx.x, j = tid & 31, h = tid >> 5;
  float g = fmaxf(gamma[0], 0.01f);
  float igl2 = (1.0f / g) * 1.4426950408889634f;
  float gln2 = g * 0.6931471805599453f;
  const float* Utc = sg.Ut + (size_t)chain * T * 32;
  float* Oc = (isB ? sg.B : sg.F) + (size_t)chain * T * 32;
  const float4* src = (const float4*)(sg.PT + (size_t)chain * sg.Tpad * 1024);
  int nch = sg.Tpad / TC;
  int perm3 = (j >> 1) & 7;
  int gbase = h * 48;
  float4 stg[4];
  if (!isB) {
    float cur = Utc[j];
    if (h == 0) f_out[j] = cur;                    // slot 0 (t=0)
    #pragma unroll
    for (int q = 0; q < 4; q++) stg[q] = src[q * 64 + tid];
    int buf = 0;
    for (int ch = 0; ch < nch; ch++) {
      float4* dst = (float4*)(lds + buf * CHUNK_BYTES);
      #pragma unroll
      for (int q = 0; q < 4; q++) dst[q * 64 + tid] = stg[q];
      if (ch + 1 < nch) {
        const float4* s2 = src + (size_t)(ch + 1) * CHUNK_F4;
        #pragma unroll
        for (int q = 0; q < 4; q++) stg[q] = s2[q * 64 + tid];
      }
      #pragma unroll
      for (int ss = 0; ss < TC; ss++) {
        int s = ch * TC + ss;
        if (s >= Tt) break;
        const uint32_t* sl = (const uint32_t*)(lds + buf * CHUNK_BYTES + ss * 2048);
        float v[16];
        #pragma unroll
        for (int rr = 0; rr < 4; rr++) {
          int pos = (4 * h + rr) ^ perm3;
          uint2 dv = *(const uint2*)&sl[j * 16 + pos * 2];
          v[rr * 4 + 0] = __uint_as_float(dv.x << 16);
          v[rr * 4 + 1] = __uint_as_float(dv.x & 0xFFFF0000u);
          v[rr * 4 + 2] = __uint_as_float(dv.y << 16);
          v[rr * 4 + 3] = __uint_as_float(dv.y & 0xFFFF0000u);
        }
        #pragma unroll
        for (int q = 0; q < 16; q++) v[q] += __shfl(cur, gbase + q);
        int t = s + 1;
        float uval = Utc[(size_t)t * 32 + j];
        cur = lse16x2(v, igl2, gln2, uval);
        if (h == 0) f_out[(t & 7) * 32 + j] = cur;
        if ((t & 7) == 7) {
          float4 vv = *(float4*)&f_out[tid * 4];
          *(float4*)&Oc[(size_t)(t - 7) * 32 + tid * 4] = vv;
        }
      }
      buf ^= 1;
    }
  } else {
    int p2i = j >> 2, pri = (j >> 1) & 1, loi = j & 1;
    float cur = Utc[(size_t)(T - 1) * 32 + j];
    if (h == 0) f_out[7 * 32 + j] = cur;           // slot 7 (t=T-1)
    {
      const float4* s2 = src + (size_t)(nch - 1) * CHUNK_F4;
      #pragma unroll
      for (int q = 0; q < 4; q++) stg[q] = s2[q * 64 + tid];
    }
    int buf = 0;
    for (int ch = nch - 1; ch >= 0; ch--) {
      float4* dst = (float4*)(lds + buf * CHUNK_BYTES);
      #pragma unroll
      for (int q = 0; q < 4; q++) dst[q * 64 + tid] = stg[q];
      if (ch > 0) {
        const float4* s2 = src + (size_t)(ch - 1) * CHUNK_F4;
        #pragma unroll
        for (int q = 0; q < 4; q++) stg[q] = s2[q * 64 + tid];
      }
      #pragma unroll
      for (int ss = TC - 1; ss >= 0; ss--) {
        int s = ch * TC + ss;
        if (s >= Tt) continue;
        const uint16_t* row16 = (const uint16_t*)(lds + buf * CHUNK_BYTES + ss * 2048);
        float v[16];
        #pragma unroll
        for (int jj = 0; jj < 16; jj++) {
          int u16idx = (16 * h + jj) * 32 + ((p2i ^ (jj >> 1)) * 2 + pri) * 2 + loi;
          v[jj] = __uint_as_float((uint32_t)row16[u16idx] << 16);
        }
        #pragma unroll
        for (int q = 0; q < 16; q++) v[q] += __shfl(cur, gbase + q);
        float uval = Utc[(size_t)s * 32 + j];
        cur = lse16x2(v, igl2, gln2, uval);
        if (h == 0) f_out[(s & 7) * 32 + j] = cur;
        if ((s & 7) == 0) {
          float4 vv = *(float4*)&f_out[tid * 4];
          *(float4*)&Oc[(size_t)s * 32 + tid * 4] = vv;
        }
      }
      buf ^= 1;
    }
  }
}

// ---------- marginals: softmax((F+B-Ut)/g) over c, float4 coalesced write ----------
__global__ __launch_bounds__(256) void k_marg_all(MTable tbl, const float* __restrict__ gamma)
{
  __shared__ float sm[32][33];
  int bid = blockIdx.x;
  int k = 0;
  for (int q = 1; q < tbl.nseg; q++) if (bid >= tbl.s[q].blockBase) k = q;
  MSeg sg = tbl.s[k];
  int r = bid - sg.blockBase;
  int rx = r % sg.nrx; int tmp = r / sg.nrx;
  int fx = tmp % sg.nfx; int b = tmp / sg.nfx;
  int tid = threadIdx.x;
  float g = fmaxf(gamma[0], 0.01f);
  float ig = 1.0f / g;
  int c = tid & 31;
  int L = sg.L, T = sg.T;
  size_t LT = (size_t)L * T;
  int RA = sg.dirV ? L : T;
  int r0 = rx * 32;
  #pragma unroll
  for (int pass = 0; pass < 4; pass++) {
    int rr = (tid >> 5) + pass * 8;
    int rowAxis = r0 + rr;
    int chain = sg.dirV ? b * L + rowAxis : b * L + fx;
    int t = sg.dirV ? fx : rowAxis;
    size_t idx = ((size_t)chain * T + t) * 32 + c;
    float z = (sg.F[idx] + sg.B[idx] - sg.Ut[idx]) * ig;
    sm[rr][c] = softmax32(z);
  }
  __syncthreads();
  int cc = tid >> 3;
  int xl = (tid & 7) * 4;
  size_t obase = (size_t)b * 32 * LT + (size_t)fx * RA + r0;
  float4 vv = make_float4(sm[xl][cc], sm[xl + 1][cc], sm[xl + 2][cc], sm[xl + 3][cc]);
  *(float4*)&sg.out[obase + (size_t)cc * LT + xl] = vv;
}

// ---------- combine: float4 everywhere ----------
__global__ __launch_bounds__(256) void k_combine(
    const float* __restrict__ uh0, const float* __restrict__ uv0,
    const float* __restrict__ MB, float* __restrict__ out)
{
  int t4 = blockIdx.x * 256 + threadIdx.x;   // float4 index over 2*32*128*128/4
  int base = t4 * 4;
  int x = base & 127, y = (base >> 7) & 127;
  int bc = base >> 14;
  float4 mh0 = *(const float4*)&MB[base];
  float4 mv0 = *(const float4*)&MB[1048576 + base];
  int ce = 1 + ((y & 1) << 1);
  int coff = bc * 4096 + ((y >> 1) << 6) + (x >> 1);
  const float* cbE = MB + 2097152 + (size_t)(ce - 1) * 524288;
  const float* cbO = cbE + 524288;
  float2 mhcE = *(const float2*)&cbE[coff];
  float2 mhcO = *(const float2*)&cbO[coff];
  float2 mvcE = *(const float2*)&cbE[262144 + coff];
  float2 mvcO = *(const float2*)&cbO[262144 + coff];
  float4 u_h = *(const float4*)&uh0[base];
  float4 u_v = *(const float4*)&uv0[base];
  float mh[4] = {mh0.x, mh0.y, mh0.z, mh0.w};
  float mv[4] = {mv0.x, mv0.y, mv0.z, mv0.w};
  float uh[4] = {u_h.x, u_h.y, u_h.z, u_h.w};
  float uv[4] = {u_v.x, u_v.y, u_v.z, u_v.w};
  float mhc[4] = {mhcE.x, mhcO.x, mhcE.y, mhcO.y};
  float mvc[4] = {mvcE.x, mvcO.x, mvcE.y, mvcO.y};
  float o0[4], o1[4], o2[4], o3[4];
  const float A = 0.0078125f;
  #pragma unroll
  for (int e = 0; e < 4; e++) {
    float mha = mh[e] + mhc[e], mva = mv[e] + mvc[e];
    float avg = (mha + mva) * 0.25f;
    o0[e] = uh[e] - A * (mh[e] - avg);
    o1[e] = uv[e] - A * (mv[e] - avg);
    o2[e] = mha; o3[e] = mva;
  }
  *(float4*)&out[base]           = make_float4(o0[0], o0[1], o0[2], o0[3]);
  *(float4*)&out[1048576 + base] = make_float4(o1[0], o1[1], o1[2], o1[3]);
  *(float4*)&out[2097152 + base] = make_float4(o2[0], o2[1], o2[2], o2[3]);
  *(float4*)&out[3145728 + base] = make_float4(o3[0], o3[1], o3[2], o3[3]);
}

// ---------- launch ----------
static void fill_tseg(TSeg& t, const float* pw, uint16_t* PT, int L, int T, int dirV, int blockBase)
{
  int Tt = T - 1;
  t.pw = pw; t.PT = PT;
  t.L = L; t.Tt = Tt; t.Tpad = T;
  t.fStride = dirV ? L : Tt;
  t.Xtot = dirV ? L : Tt;
  t.dirV = dirV;
  int pad = (t.fStride & 31) ? 31 : 0;
  t.nx = (t.Xtot + pad + 127) / 128;
  t.ny = dirV ? Tt : L;
  t.blockBase = blockBase;
}

extern "C" void kernel_launch(void* const* d_in, const int* in_sizes, int n_in,
                              void* d_out, int out_size, void* d_ws, size_t ws_size,
                              hipStream_t stream)
{
  (void)in_sizes; (void)n_in; (void)out_size;
  const float* gamma = (const float*)d_in[20];
  unsigned char* ws = (unsigned char*)d_ws;

  int segL[10], segT[10];
  const float* segPW[10]; const float* segUU[10];
  size_t segMG[10];
  for (int lvl = 0; lvl < 5; lvl++) {
    int H = lvl ? 64 : 128, W = H;
    int si = lvl * 2;
    segL[si] = H; segT[si] = W;
    segPW[si] = (const float*)d_in[lvl * 4 + 2];
    segUU[si] = (const float*)d_in[lvl * 4 + 0];
    segL[si + 1] = W; segT[si + 1] = H;
    segPW[si + 1] = (const float*)d_in[lvl * 4 + 3];
    segUU[si + 1] = (const float*)d_in[lvl * 4 + 1];
    if (lvl == 0) { segMG[0] = 0; segMG[1] = 1048576; }
    else { segMG[si] = 2097152 + (size_t)(lvl - 1) * 524288; segMG[si + 1] = segMG[si] + 262144; }
  }

  const size_t NEED = 318767104ull;
  if (ws_size >= NEED) {
    uint16_t* PT0 = (uint16_t*)ws;
    float* MARG = (float*)ws;                       // aliased over PT, used after DP
    float* F0  = (float*)(ws + 268435456ull);
    float* B0  = (float*)(ws + 285212672ull);
    float* Ut0 = (float*)(ws + 301989888ull);

    TTable tt; UTable ut; DTable dt; MTable mt;
    tt.nseg = 10; ut.nseg = 10; dt.nseg = 10; mt.nseg = 10;
    size_t ptOff = 0, fuOff = 0;
    int tB = 0, uB = 0, cB = 0, mB = 0;
    for (int s = 0; s < 10; s++) {
      int dirV = s & 1;
      int L = segL[s], T = segT[s];
      int chains = 2 * L;
      fill_tseg(tt.s[s], segPW[s], PT0 + ptOff, L, T, dirV, tB);
      tB += 2 * tt.s[s].ny * tt.s[s].nx * 8;
      USeg& u = ut.s[s];
      u.U = segUU[s]; u.Ut = Ut0 + fuOff;
      u.fs = dirV ? L : T;
      u.nx = (dirV ? L : T) / 32;
      u.ny = dirV ? T : L;
      u.L = L; u.T = T; u.dirV = dirV;
      u.blockBase = uB;
      uB += u.nx * u.ny * 2;
      DSeg& d = dt.s[s];
      d.PT = PT0 + ptOff; d.Ut = Ut0 + fuOff;
      d.F = F0 + fuOff; d.B = B0 + fuOff;
      d.chainBase = cB; d.T = T; d.Tt = T - 1; d.Tpad = T;
      cB += chains;
      MSeg& m = mt.s[s];
      m.F = F0 + fuOff; m.B = B0 + fuOff; m.Ut = Ut0 + fuOff;
      m.out = MARG + segMG[s];
      m.L = L; m.T = T; m.dirV = dirV;
      m.blockBase = mB;
      m.nrx = (dirV ? L : T) / 32;
      m.nfx = dirV ? T : L;
      mB += 2 * m.nfx * m.nrx;
      ptOff += (size_t)chains * T * 1024;
      fuOff += (size_t)chains * T * 32;
    }
    k_transpose_all<<<tB, 256, 0, stream>>>(tt);
    k_ut_all<<<uB, 256, 0, stream>>>(ut);
    k_dp_all<<<2 * cB, 64, 0, stream>>>(dt, gamma, cB);
    k_marg_all<<<mB, 256, 0, stream>>>(mt, gamma);
    k_combine<<<1024, 256, 0, stream>>>((const float*)d_in[0], (const float*)d_in[1],
                                        MARG, (float*)d_out);
  } else {
    // level-serial fallback
    uint16_t* PT0 = (uint16_t*)ws;
    float* F0  = (float*)(ws + 67108864ull);
    float* B0  = (float*)(ws + 71303168ull);
    float* Ut0 = (float*)(ws + 75497472ull);
    float* MARG = (float*)(ws + 79691776ull);
    for (int s = 0; s < 10; s++) {
      int dirV = s & 1;
      int L = segL[s], T = segT[s];
      int chains = 2 * L;
      TTable tt; tt.nseg = 1;
      fill_tseg(tt.s[0], segPW[s], PT0, L, T, dirV, 0);
      int nb = 2 * tt.s[0].ny * tt.s[0].nx * 8;
      k_transpose_all<<<nb, 256, 0, stream>>>(tt);
      UTable ut; ut.nseg = 1;
      USeg& u = ut.s[0];
      u.U = segUU[s]; u.Ut = Ut0;
      u.fs = dirV ? L : T;
      u.nx = (dirV ? L : T) / 32;
      u.ny = dirV ? T : L;
      u.L = L; u.T = T; u.dirV = dirV; u.blockBase = 0;
      int ub = u.nx * u.ny * 2;
      k_ut_all<<<ub, 256, 0, stream>>>(ut);
      DTable dt; dt.nseg = 1;
      DSeg& d = dt.s[0];
      d.PT = PT0; d.Ut = Ut0; d.F = F0; d.B = B0;
      d.chainBase = 0; d.T = T; d.Tt = T - 1; d.Tpad = T;
      k_dp_all<<<2 * chains, 64, 0, stream>>>(dt, gamma, chains);
      MTable mt; mt.nseg = 1;
      MSeg& m = mt.s[0];
      m.F = F0; m.B = B0; m.Ut = Ut0; m.out = MARG + segMG[s];
      m.L = L; m.T = T; m.dirV = dirV; m.blockBase = 0;
      m.nrx = (dirV ? L : T) / 32;
      m.nfx = dirV ? T : L;
      int mb = 2 * m.nfx * m.nrx;
      k_marg_all<<<mb, 256, 0, stream>>>(mt, gamma);
    }
    k_combine<<<1024, 256, 0, stream>>>((const float*)d_in[0], (const float*)d_in[1],
                                        MARG, (float*)d_out);
  }
}